// Round 1
// baseline (4172.507 us; speedup 1.0000x reference)
//
#include <hip/hip_runtime.h>
#include <math.h>

#define HEADS 4
#define CPH 256
#define DHID 1024
#define NEG_SLOPE 0.2f
#define FLT_BIG 3.402823466e38f

__device__ __forceinline__ float lrelu(float x){ return x > 0.f ? x : NEG_SLOPE * x; }
__device__ __forceinline__ float eluf(float x){ return x > 0.f ? x : expf(x) - 1.f; }

// ---------------- CSR build + pooling bounds ----------------
__global__ void k_init(int* cnt, int* fill, int* lo, int* hi, int N, int G){
    int i = blockIdx.x * blockDim.x + threadIdx.x;
    if (i < N){ cnt[i] = 0; fill[i] = 0; }
    if (i < G){ lo[i] = 0x7fffffff; hi[i] = 0; }
}

__global__ void k_count(const int* __restrict__ dst, int* __restrict__ cnt, int E){
    int e = blockIdx.x * blockDim.x + threadIdx.x;
    if (e < E) atomicAdd(&cnt[dst[e]], 1);
}

__global__ __launch_bounds__(1024) void k_scan(const int* __restrict__ cnt, int* __restrict__ rowptr,
                                               int N, int E){
    __shared__ int tot[1024];
    int tid = threadIdx.x;
    int items = (N + 1023) >> 10;
    int base = tid * items;
    int sum = 0;
    for (int i = 0; i < items; ++i){ int idx = base + i; if (idx < N) sum += cnt[idx]; }
    tot[tid] = sum;
    __syncthreads();
    for (int off = 1; off < 1024; off <<= 1){
        int t = (tid >= off) ? tot[tid - off] : 0;
        __syncthreads();
        tot[tid] += t;
        __syncthreads();
    }
    int run = tot[tid] - sum;   // exclusive prefix of this thread's chunk
    for (int i = 0; i < items; ++i){
        int idx = base + i;
        if (idx < N){ rowptr[idx] = run; run += cnt[idx]; }
    }
    if (tid == 0) rowptr[N] = E;
}

__global__ void k_scatter(const int* __restrict__ src, const int* __restrict__ dst,
                          const int* __restrict__ rowptr, int* __restrict__ fill,
                          int* __restrict__ col, int E){
    int e = blockIdx.x * blockDim.x + threadIdx.x;
    if (e < E){
        int d = dst[e];
        int pos = rowptr[d] + atomicAdd(&fill[d], 1);
        col[pos] = src[e];
    }
}

__global__ void k_bounds(const int* __restrict__ batch, int* lo, int* hi, int N){
    int i = blockIdx.x * blockDim.x + threadIdx.x;
    if (i < N){
        int b = batch[i];
        atomicMin(&lo[b], i);
        atomicMax(&hi[b], i + 1);
    }
}

// ---------------- fp32 tiled GEMM: C = A(MxK) @ B(KxN) ----------------
#define BM 128
#define BN 128
#define BK 16
__global__ __launch_bounds__(256) void k_gemm(const float* __restrict__ A, const float* __restrict__ B,
                                              float* __restrict__ C, int M, int K, int Nn){
    __shared__ float As[BK][BM];
    __shared__ float Bs[BK][BN];
    int tid = threadIdx.x;
    int tx = tid & 15, ty = tid >> 4;
    int row0 = blockIdx.y * BM, col0 = blockIdx.x * BN;
    float acc[8][8];
#pragma unroll
    for (int i = 0; i < 8; ++i)
#pragma unroll
        for (int j = 0; j < 8; ++j) acc[i][j] = 0.f;

    for (int k0 = 0; k0 < K; k0 += BK){
#pragma unroll
        for (int l = 0; l < 2; ++l){       // A tile: 128x16 = 512 float4
            int f = tid + l * 256;
            int r = f >> 2, cc = (f & 3) << 2;
            int gr = row0 + r;
            float4 v = make_float4(0.f, 0.f, 0.f, 0.f);
            if (gr < M) v = *(const float4*)(A + (size_t)gr * K + k0 + cc);
            As[cc + 0][r] = v.x; As[cc + 1][r] = v.y; As[cc + 2][r] = v.z; As[cc + 3][r] = v.w;
        }
#pragma unroll
        for (int l = 0; l < 2; ++l){       // B tile: 16x128 = 512 float4
            int f = tid + l * 256;
            int r = f >> 5, cc = (f & 31) << 2;
            float4 v = *(const float4*)(B + (size_t)(k0 + r) * Nn + col0 + cc);
            *(float4*)(&Bs[r][cc]) = v;
        }
        __syncthreads();
#pragma unroll
        for (int kk = 0; kk < BK; ++kk){
            float a[8], b[8];
#pragma unroll
            for (int i = 0; i < 8; ++i) a[i] = As[kk][ty * 8 + i];
#pragma unroll
            for (int j = 0; j < 8; ++j) b[j] = Bs[kk][tx * 8 + j];
#pragma unroll
            for (int i = 0; i < 8; ++i)
#pragma unroll
                for (int j = 0; j < 8; ++j) acc[i][j] += a[i] * b[j];
        }
        __syncthreads();
    }
#pragma unroll
    for (int i = 0; i < 8; ++i){
        int gr = row0 + ty * 8 + i;
        if (gr < M){
            float4 v0 = make_float4(acc[i][0], acc[i][1], acc[i][2], acc[i][3]);
            float4 v1 = make_float4(acc[i][4], acc[i][5], acc[i][6], acc[i][7]);
            *(float4*)(C + (size_t)gr * Nn + col0 + tx * 8)     = v0;
            *(float4*)(C + (size_t)gr * Nn + col0 + tx * 8 + 4) = v1;
        }
    }
}

// ---------------- per-node attention score dots ----------------
// block = node, wave w = head w, lane handles one float4 of the 256 channels
__global__ __launch_bounds__(256) void k_esd(const float* __restrict__ h, const float* __restrict__ asrc,
                                             const float* __restrict__ adst,
                                             float* __restrict__ es, float* __restrict__ ed){
    int n = blockIdx.x;
    int tid = threadIdx.x;
    int w = tid >> 6, lane = tid & 63;
    const float4* hp = (const float4*)(h + (size_t)n * DHID + w * CPH);
    const float4* ap = (const float4*)(asrc + w * CPH);
    const float4* dp = (const float4*)(adst + w * CPH);
    float4 hv = hp[lane], av = ap[lane], dv = dp[lane];
    float s = hv.x * av.x + hv.y * av.y + hv.z * av.z + hv.w * av.w;
    float d = hv.x * dv.x + hv.y * dv.y + hv.z * dv.z + hv.w * dv.w;
    for (int off = 32; off > 0; off >>= 1){
        s += __shfl_down(s, off);
        d += __shfl_down(d, off);
    }
    if (lane == 0){ es[n * HEADS + w] = s; ed[n * HEADS + w] = d; }
}

// ---------------- per-dst-node segment softmax + aggregation + bias + elu ----------------
__global__ __launch_bounds__(256) void k_agg(const float* __restrict__ hsrc, const float* __restrict__ es,
                                             const float* __restrict__ ed, const int* __restrict__ rowptr,
                                             const int* __restrict__ col, const float* __restrict__ bias,
                                             float* __restrict__ out){
    int n = blockIdx.x;
    int tid = threadIdx.x;
    int w = tid >> 6, lane = tid & 63;
    int rp0 = rowptr[n];
    int deg = rowptr[n + 1] - rp0;
    int total = deg + 1;                       // + implicit self-loop
    float4 edv = *(const float4*)(ed + (size_t)n * HEADS);

    __shared__ float4 sred[4];
    __shared__ float4 sbc;

    // ---- phase 1: per-head max of e over incoming edges ----
    float4 mx = make_float4(-FLT_BIG, -FLT_BIG, -FLT_BIG, -FLT_BIG);
    for (int i = tid; i < total; i += 256){
        int s = (i < deg) ? col[rp0 + i] : n;
        float4 ev = *(const float4*)(es + (size_t)s * HEADS);
        mx.x = fmaxf(mx.x, lrelu(ev.x + edv.x));
        mx.y = fmaxf(mx.y, lrelu(ev.y + edv.y));
        mx.z = fmaxf(mx.z, lrelu(ev.z + edv.z));
        mx.w = fmaxf(mx.w, lrelu(ev.w + edv.w));
    }
    for (int off = 32; off > 0; off >>= 1){
        mx.x = fmaxf(mx.x, __shfl_down(mx.x, off));
        mx.y = fmaxf(mx.y, __shfl_down(mx.y, off));
        mx.z = fmaxf(mx.z, __shfl_down(mx.z, off));
        mx.w = fmaxf(mx.w, __shfl_down(mx.w, off));
    }
    if (lane == 0) sred[w] = mx;
    __syncthreads();
    if (tid == 0){
        float4 a = sred[0], b = sred[1], c = sred[2], d = sred[3];
        a.x = fmaxf(fmaxf(a.x, b.x), fmaxf(c.x, d.x));
        a.y = fmaxf(fmaxf(a.y, b.y), fmaxf(c.y, d.y));
        a.z = fmaxf(fmaxf(a.z, b.z), fmaxf(c.z, d.z));
        a.w = fmaxf(fmaxf(a.w, b.w), fmaxf(c.w, d.w));
        sbc = a;
    }
    __syncthreads();
    float4 m4 = sbc;

    // ---- phase 2: per-head sum of exp(e - m) ----
    float4 sm = make_float4(0.f, 0.f, 0.f, 0.f);
    for (int i = tid; i < total; i += 256){
        int s = (i < deg) ? col[rp0 + i] : n;
        float4 ev = *(const float4*)(es + (size_t)s * HEADS);
        sm.x += expf(lrelu(ev.x + edv.x) - m4.x);
        sm.y += expf(lrelu(ev.y + edv.y) - m4.y);
        sm.z += expf(lrelu(ev.z + edv.z) - m4.z);
        sm.w += expf(lrelu(ev.w + edv.w) - m4.w);
    }
    for (int off = 32; off > 0; off >>= 1){
        sm.x += __shfl_down(sm.x, off);
        sm.y += __shfl_down(sm.y, off);
        sm.z += __shfl_down(sm.z, off);
        sm.w += __shfl_down(sm.w, off);
    }
    if (lane == 0) sred[w] = sm;
    __syncthreads();
    if (tid == 0){
        float4 a = sred[0], b = sred[1], c = sred[2], d = sred[3];
        a.x += b.x + c.x + d.x;
        a.y += b.y + c.y + d.y;
        a.z += b.z + c.z + d.z;
        a.w += b.w + c.w + d.w;
        sbc = a;
    }
    __syncthreads();
    float4 s4 = sbc;

    // ---- phase 3: weighted aggregation; wave w owns head w's 256 channels ----
    float myM  = (w == 0) ? m4.x  : (w == 1) ? m4.y  : (w == 2) ? m4.z  : m4.w;
    float myS  = (w == 0) ? s4.x  : (w == 1) ? s4.y  : (w == 2) ? s4.z  : s4.w;
    float myEd = (w == 0) ? edv.x : (w == 1) ? edv.y : (w == 2) ? edv.z : edv.w;
    float myInv = 1.f / (myS + 1e-16f);
    int cidx = w * CPH + lane * 4;
    float4 acc = make_float4(0.f, 0.f, 0.f, 0.f);
    for (int i = 0; i < total; ++i){
        int s = (i < deg) ? col[rp0 + i] : n;       // wave-uniform
        float ei = es[(size_t)s * HEADS + w];        // broadcast load
        float alpha = expf(lrelu(ei + myEd) - myM) * myInv;
        float4 hv = *(const float4*)(hsrc + (size_t)s * DHID + cidx);
        acc.x += alpha * hv.x;
        acc.y += alpha * hv.y;
        acc.z += alpha * hv.z;
        acc.w += alpha * hv.w;
    }
    float4 bv = *(const float4*)(bias + cidx);
    float4 o;
    o.x = eluf(acc.x + bv.x);
    o.y = eluf(acc.y + bv.y);
    o.z = eluf(acc.z + bv.z);
    o.w = eluf(acc.w + bv.w);
    *(float4*)(out + (size_t)n * DHID + cidx) = o;
}

// ---------------- per-graph mean/max pooling ----------------
__global__ __launch_bounds__(256) void k_pool(const float* __restrict__ hf, const int* __restrict__ lo,
                                              const int* __restrict__ hi, float* __restrict__ gfeat){
    int g = blockIdx.x;
    int tid = threadIdx.x;
    int l = lo[g], h2 = hi[g];
    int cntn = (h2 > l) ? (h2 - l) : 0;
    int c = tid * 4;
    float4 sum = make_float4(0.f, 0.f, 0.f, 0.f);
    float4 mx = make_float4(-FLT_BIG, -FLT_BIG, -FLT_BIG, -FLT_BIG);
    for (int i = l; i < h2; ++i){
        float4 v = *(const float4*)(hf + (size_t)i * DHID + c);
        sum.x += v.x; sum.y += v.y; sum.z += v.z; sum.w += v.w;
        mx.x = fmaxf(mx.x, v.x); mx.y = fmaxf(mx.y, v.y);
        mx.z = fmaxf(mx.z, v.z); mx.w = fmaxf(mx.w, v.w);
    }
    float invc = 1.f / (float)((cntn > 1) ? cntn : 1);
    float4 mean = make_float4(sum.x * invc, sum.y * invc, sum.z * invc, sum.w * invc);
    if (cntn == 0) mx = make_float4(0.f, 0.f, 0.f, 0.f);
    *(float4*)(gfeat + (size_t)g * 2048 + c)        = mean;
    *(float4*)(gfeat + (size_t)g * 2048 + 1024 + c) = mx;
}

// ---------------- small FC: Y[r,c] = act(X[r,:]@W[:,c] + b[c]) ----------------
__global__ __launch_bounds__(256) void k_fc(const float* __restrict__ X, const float* __restrict__ W,
                                            const float* __restrict__ b, float* __restrict__ Y,
                                            int K, int Nc, int relu){
    __shared__ float xr[2048];
    int r = blockIdx.y;
    int tid = threadIdx.x;
    for (int i = tid; i < K; i += 256) xr[i] = X[(size_t)r * K + i];
    __syncthreads();
    int c = blockIdx.x * 256 + tid;
    if (c >= Nc) return;
    float acc = b[c];
    for (int k = 0; k < K; ++k) acc += xr[k] * W[(size_t)k * Nc + c];
    if (relu) acc = fmaxf(acc, 0.f);
    Y[(size_t)r * Nc + c] = acc;
}

// ---------------- launch ----------------
extern "C" void kernel_launch(void* const* d_in, const int* in_sizes, int n_in,
                              void* d_out, int out_size, void* d_ws, size_t ws_size,
                              hipStream_t stream) {
    const float* x      = (const float*)d_in[0];
    const int*   ei     = (const int*)  d_in[1];
    const int*   batch  = (const int*)  d_in[2];
    const float* W1     = (const float*)d_in[3];
    const float* asrc1  = (const float*)d_in[4];
    const float* adst1  = (const float*)d_in[5];
    const float* b1     = (const float*)d_in[6];
    const float* W2     = (const float*)d_in[7];
    const float* asrc2  = (const float*)d_in[8];
    const float* adst2  = (const float*)d_in[9];
    const float* b2     = (const float*)d_in[10];
    const float* Wc1    = (const float*)d_in[11];
    const float* bc1    = (const float*)d_in[12];
    const float* Wc2    = (const float*)d_in[13];
    const float* bc2    = (const float*)d_in[14];
    const float* Wc3    = (const float*)d_in[15];
    const float* bc3    = (const float*)d_in[16];

    const int N = in_sizes[2];          // 50000
    const int E = in_sizes[1] / 2;      // 200000
    const int G = out_size / 5;         // 64
    const int DIN = in_sizes[0] / N;    // 768

    const int* srcI = ei;
    const int* dstI = ei + E;

    // workspace bump allocator (256B aligned regions)
    char* p = (char*)d_ws;
    auto alloc = [&](size_t bytes) -> void* {
        void* q = (void*)p;
        p += (bytes + 255) & ~(size_t)255;
        return q;
    };
    float* hbuf   = (float*)alloc((size_t)N * DHID * 4);
    float* xbuf   = (float*)alloc((size_t)N * DHID * 4);
    float* es     = (float*)alloc((size_t)N * HEADS * 4);
    float* ed     = (float*)alloc((size_t)N * HEADS * 4);
    float* gfeat  = (float*)alloc((size_t)G * 2048 * 4);
    float* z1     = (float*)alloc((size_t)G * 512 * 4);
    float* z2     = (float*)alloc((size_t)G * 256 * 4);
    int*   cnt    = (int*)  alloc((size_t)N * 4);
    int*   fill   = (int*)  alloc((size_t)N * 4);
    int*   rowptr = (int*)  alloc((size_t)(N + 1) * 4);
    int*   col    = (int*)  alloc((size_t)E * 4);
    int*   lo     = (int*)  alloc((size_t)G * 4);
    int*   hi     = (int*)  alloc((size_t)G * 4);
    float* logits = (float*)d_out;

    int nb = (N + 255) / 256;
    int ebp = (E + 255) / 256;

    // CSR + pooling bounds
    k_init   <<<nb,  256, 0, stream>>>(cnt, fill, lo, hi, N, G);
    k_count  <<<ebp, 256, 0, stream>>>(dstI, cnt, E);
    k_scan   <<<1,  1024, 0, stream>>>(cnt, rowptr, N, E);
    k_scatter<<<ebp, 256, 0, stream>>>(srcI, dstI, rowptr, fill, col, E);
    k_bounds <<<nb,  256, 0, stream>>>(batch, lo, hi, N);

    dim3 gemmBlk(256);
    dim3 gemmGrd1(DHID / BN, (N + BM - 1) / BM);

    // ---- GAT layer 1 ----
    k_gemm<<<gemmGrd1, gemmBlk, 0, stream>>>(x, W1, hbuf, N, DIN, DHID);
    k_esd <<<N, 256, 0, stream>>>(hbuf, asrc1, adst1, es, ed);
    k_agg <<<N, 256, 0, stream>>>(hbuf, es, ed, rowptr, col, b1, xbuf);

    // ---- GAT layer 2 ----
    k_gemm<<<gemmGrd1, gemmBlk, 0, stream>>>(xbuf, W2, hbuf, N, DHID, DHID);
    k_esd <<<N, 256, 0, stream>>>(hbuf, asrc2, adst2, es, ed);
    k_agg <<<N, 256, 0, stream>>>(hbuf, es, ed, rowptr, col, b2, xbuf);

    // ---- pooling + classifier ----
    k_pool<<<G, 256, 0, stream>>>(xbuf, lo, hi, gfeat);
    k_fc<<<dim3(2, G), 256, 0, stream>>>(gfeat, Wc1, bc1, z1, 2048, 512, 1);
    k_fc<<<dim3(1, G), 256, 0, stream>>>(z1,    Wc2, bc2, z2, 512,  256, 1);
    k_fc<<<dim3(1, G), 256, 0, stream>>>(z2,    Wc3, bc3, logits, 256, 5, 0);
}

// Round 2
// 2524.475 us; speedup vs baseline: 1.6528x; 1.6528x over previous
//
#include <hip/hip_runtime.h>
#include <math.h>

#define HEADS 4
#define CPH 256
#define DHID 1024
#define NEG_SLOPE 0.2f
#define FLT_BIG 3.402823466e38f

typedef unsigned short u16;
typedef __bf16 bf16x8 __attribute__((ext_vector_type(8)));
typedef float f32x4 __attribute__((ext_vector_type(4)));

__device__ __forceinline__ float lrelu(float x){ return x > 0.f ? x : NEG_SLOPE * x; }
__device__ __forceinline__ float eluf(float x){ return x > 0.f ? x : expf(x) - 1.f; }

// ---- fp32 -> bf16 split helpers (RNE) ----
__device__ __forceinline__ u16 f2bf(float f){
    unsigned u = __float_as_uint(f);
    u += 0x7fffu + ((u >> 16) & 1u);
    return (u16)(u >> 16);
}
__device__ __forceinline__ float bf2f(u16 h){ return __uint_as_float(((unsigned)h) << 16); }

__device__ __forceinline__ void gload_lds16(const void* g, void* l){
    __builtin_amdgcn_global_load_lds((const __attribute__((address_space(1))) unsigned int*)g,
                                     (__attribute__((address_space(3))) unsigned int*)l, 16, 0, 0);
}

// ---------------- CSR build + pooling bounds ----------------
__global__ void k_init(int* cnt, int* fill, int* lo, int* hi, int N, int G){
    int i = blockIdx.x * blockDim.x + threadIdx.x;
    if (i < N){ cnt[i] = 0; fill[i] = 0; }
    if (i < G){ lo[i] = 0x7fffffff; hi[i] = 0; }
}

__global__ void k_count(const int* __restrict__ dst, int* __restrict__ cnt, int E){
    int e = blockIdx.x * blockDim.x + threadIdx.x;
    if (e < E) atomicAdd(&cnt[dst[e]], 1);
}

__global__ __launch_bounds__(1024) void k_scan(const int* __restrict__ cnt, int* __restrict__ rowptr,
                                               int N, int E){
    __shared__ int tot[1024];
    int tid = threadIdx.x;
    int items = (N + 1023) >> 10;
    int base = tid * items;
    int sum = 0;
    for (int i = 0; i < items; ++i){ int idx = base + i; if (idx < N) sum += cnt[idx]; }
    tot[tid] = sum;
    __syncthreads();
    for (int off = 1; off < 1024; off <<= 1){
        int t = (tid >= off) ? tot[tid - off] : 0;
        __syncthreads();
        tot[tid] += t;
        __syncthreads();
    }
    int run = tot[tid] - sum;
    for (int i = 0; i < items; ++i){
        int idx = base + i;
        if (idx < N){ rowptr[idx] = run; run += cnt[idx]; }
    }
    if (tid == 0) rowptr[N] = E;
}

__global__ void k_scatter(const int* __restrict__ src, const int* __restrict__ dst,
                          const int* __restrict__ rowptr, int* __restrict__ fill,
                          int* __restrict__ col, int E){
    int e = blockIdx.x * blockDim.x + threadIdx.x;
    if (e < E){
        int d = dst[e];
        int pos = rowptr[d] + atomicAdd(&fill[d], 1);
        col[pos] = src[e];
    }
}

__global__ void k_bounds(const int* __restrict__ batch, int* lo, int* hi, int N){
    int i = blockIdx.x * blockDim.x + threadIdx.x;
    if (i < N){
        int b = batch[i];
        atomicMin(&lo[b], i);
        atomicMax(&hi[b], i + 1);
    }
}

// ---------------- split kernels: fp32 -> bf16 hi/lo ----------------
__global__ void k_split(const float* __restrict__ X, u16* __restrict__ hi, u16* __restrict__ lo, long L4){
    long i = (long)blockIdx.x * blockDim.x + threadIdx.x;
    if (i < L4){
        float4 v = ((const float4*)X)[i];
        ushort4 h, l;
        h.x = f2bf(v.x); l.x = f2bf(v.x - bf2f(h.x));
        h.y = f2bf(v.y); l.y = f2bf(v.y - bf2f(h.y));
        h.z = f2bf(v.z); l.z = f2bf(v.z - bf2f(h.z));
        h.w = f2bf(v.w); l.w = f2bf(v.w - bf2f(h.w));
        ((ushort4*)hi)[i] = h;
        ((ushort4*)lo)[i] = l;
    }
}

// W (KxN fp32, row-major) -> WT hi/lo (NxK bf16)
__global__ void k_splitT(const float* __restrict__ W, u16* __restrict__ hiT, u16* __restrict__ loT,
                         int K, int Nn){
    int idx = blockIdx.x * blockDim.x + threadIdx.x;
    if (idx < K * Nn){
        int k = idx / Nn, n = idx - k * Nn;
        float v = W[idx];
        u16 h = f2bf(v);
        hiT[(size_t)n * K + k] = h;
        loT[(size_t)n * K + k] = f2bf(v - bf2f(h));
    }
}

// ---------------- split-bf16 MFMA GEMM: C = A(MxK) @ BT(NxK)^T ----------------
// 128x128 tile, BK=32, 4 waves each computing 64x64 (4x4 of 16x16x32 MFMA tiles).
// 3-product split: C = Ah*Bh + Ah*Bl + Al*Bh  (Al*Bl dropped, ~2^-18 relative)
__global__ __launch_bounds__(256) void k_gemm_mfma(
    const u16* __restrict__ Ahi, const u16* __restrict__ Alo,
    const u16* __restrict__ BThi, const u16* __restrict__ BTlo,
    float* __restrict__ C, int M, int K, int Nn)
{
    __shared__ __align__(16) u16 As[2][128][32];   // [hi/lo][row][k] 8KB each
    __shared__ __align__(16) u16 Bs[2][128][32];
    int tid = threadIdx.x;
    int w = tid >> 6, lane = tid & 63;
    int row0 = blockIdx.y * 128, col0 = blockIdx.x * 128;

    int srow = tid >> 2;            // 0..63 staging row
    int skoff = (tid & 3) * 8;      // bf16 k-offset (0,8,16,24)

    int wm = (w >> 1) * 64, wn = (w & 1) * 64;
    int fr = lane & 15;             // fragment row within 16
    int fq = lane >> 4;             // quad (k-offset fq*8, acc rows fq*4..fq*4+3)

    f32x4 acc[4][4];
#pragma unroll
    for (int i = 0; i < 4; ++i)
#pragma unroll
        for (int j = 0; j < 4; ++j){ acc[i][j].x = 0.f; acc[i][j].y = 0.f; acc[i][j].z = 0.f; acc[i][j].w = 0.f; }

    int ra0 = row0 + srow;      if (ra0 >= M) ra0 = M - 1;
    int ra1 = row0 + srow + 64; if (ra1 >= M) ra1 = M - 1;
    int rb0 = col0 + srow;
    int rb1 = col0 + srow + 64;

    for (int k0 = 0; k0 < K; k0 += 32){
        size_t ga0 = (size_t)ra0 * K + k0 + skoff;
        size_t ga1 = (size_t)ra1 * K + k0 + skoff;
        size_t gb0 = (size_t)rb0 * K + k0 + skoff;
        size_t gb1 = (size_t)rb1 * K + k0 + skoff;
        gload_lds16(Ahi  + ga0, &As[0][srow     ][skoff]);
        gload_lds16(Ahi  + ga1, &As[0][srow + 64][skoff]);
        gload_lds16(Alo  + ga0, &As[1][srow     ][skoff]);
        gload_lds16(Alo  + ga1, &As[1][srow + 64][skoff]);
        gload_lds16(BThi + gb0, &Bs[0][srow     ][skoff]);
        gload_lds16(BThi + gb1, &Bs[0][srow + 64][skoff]);
        gload_lds16(BTlo + gb0, &Bs[1][srow     ][skoff]);
        gload_lds16(BTlo + gb1, &Bs[1][srow + 64][skoff]);
        __syncthreads();

        bf16x8 ah[4], al[4], bh[4], bl[4];
#pragma unroll
        for (int i = 0; i < 4; ++i){
            ah[i] = *(const bf16x8*)&As[0][wm + i * 16 + fr][fq * 8];
            al[i] = *(const bf16x8*)&As[1][wm + i * 16 + fr][fq * 8];
            bh[i] = *(const bf16x8*)&Bs[0][wn + i * 16 + fr][fq * 8];
            bl[i] = *(const bf16x8*)&Bs[1][wn + i * 16 + fr][fq * 8];
        }
#pragma unroll
        for (int i = 0; i < 4; ++i)
#pragma unroll
            for (int j = 0; j < 4; ++j){
                acc[i][j] = __builtin_amdgcn_mfma_f32_16x16x32_bf16(ah[i], bh[j], acc[i][j], 0, 0, 0);
                acc[i][j] = __builtin_amdgcn_mfma_f32_16x16x32_bf16(ah[i], bl[j], acc[i][j], 0, 0, 0);
                acc[i][j] = __builtin_amdgcn_mfma_f32_16x16x32_bf16(al[i], bh[j], acc[i][j], 0, 0, 0);
            }
        __syncthreads();
    }

    // epilogue: C/D layout col=lane&15, row=(lane>>4)*4+reg  [verified m89/m91]
#pragma unroll
    for (int i = 0; i < 4; ++i){
#pragma unroll
        for (int j = 0; j < 4; ++j){
            int col = col0 + wn + j * 16 + fr;
#pragma unroll
            for (int r = 0; r < 4; ++r){
                int row = row0 + wm + i * 16 + fq * 4 + r;
                if (row < M) C[(size_t)row * Nn + col] = acc[i][j][r];
            }
        }
    }
}

// ---------------- per-node attention score dots ----------------
__global__ __launch_bounds__(256) void k_esd(const float* __restrict__ h, const float* __restrict__ asrc,
                                             const float* __restrict__ adst,
                                             float* __restrict__ es, float* __restrict__ ed){
    int n = blockIdx.x;
    int tid = threadIdx.x;
    int w = tid >> 6, lane = tid & 63;
    const float4* hp = (const float4*)(h + (size_t)n * DHID + w * CPH);
    const float4* ap = (const float4*)(asrc + w * CPH);
    const float4* dp = (const float4*)(adst + w * CPH);
    float4 hv = hp[lane], av = ap[lane], dv = dp[lane];
    float s = hv.x * av.x + hv.y * av.y + hv.z * av.z + hv.w * av.w;
    float d = hv.x * dv.x + hv.y * dv.y + hv.z * dv.z + hv.w * dv.w;
    for (int off = 32; off > 0; off >>= 1){
        s += __shfl_down(s, off);
        d += __shfl_down(d, off);
    }
    if (lane == 0){ es[n * HEADS + w] = s; ed[n * HEADS + w] = d; }
}

// ---------------- per-dst-node segment softmax + aggregation + bias + elu ----------------
__global__ __launch_bounds__(256) void k_agg(const float* __restrict__ hsrc, const float* __restrict__ es,
                                             const float* __restrict__ ed, const int* __restrict__ rowptr,
                                             const int* __restrict__ col, const float* __restrict__ bias,
                                             float* __restrict__ out){
    int n = blockIdx.x;
    int tid = threadIdx.x;
    int w = tid >> 6, lane = tid & 63;
    int rp0 = rowptr[n];
    int deg = rowptr[n + 1] - rp0;
    int total = deg + 1;                       // + implicit self-loop
    float4 edv = *(const float4*)(ed + (size_t)n * HEADS);

    __shared__ float4 sred[4];
    __shared__ float4 sbc;

    float4 mx = make_float4(-FLT_BIG, -FLT_BIG, -FLT_BIG, -FLT_BIG);
    for (int i = tid; i < total; i += 256){
        int s = (i < deg) ? col[rp0 + i] : n;
        float4 ev = *(const float4*)(es + (size_t)s * HEADS);
        mx.x = fmaxf(mx.x, lrelu(ev.x + edv.x));
        mx.y = fmaxf(mx.y, lrelu(ev.y + edv.y));
        mx.z = fmaxf(mx.z, lrelu(ev.z + edv.z));
        mx.w = fmaxf(mx.w, lrelu(ev.w + edv.w));
    }
    for (int off = 32; off > 0; off >>= 1){
        mx.x = fmaxf(mx.x, __shfl_down(mx.x, off));
        mx.y = fmaxf(mx.y, __shfl_down(mx.y, off));
        mx.z = fmaxf(mx.z, __shfl_down(mx.z, off));
        mx.w = fmaxf(mx.w, __shfl_down(mx.w, off));
    }
    if (lane == 0) sred[w] = mx;
    __syncthreads();
    if (tid == 0){
        float4 a = sred[0], b = sred[1], c = sred[2], d = sred[3];
        a.x = fmaxf(fmaxf(a.x, b.x), fmaxf(c.x, d.x));
        a.y = fmaxf(fmaxf(a.y, b.y), fmaxf(c.y, d.y));
        a.z = fmaxf(fmaxf(a.z, b.z), fmaxf(c.z, d.z));
        a.w = fmaxf(fmaxf(a.w, b.w), fmaxf(c.w, d.w));
        sbc = a;
    }
    __syncthreads();
    float4 m4 = sbc;

    float4 sm = make_float4(0.f, 0.f, 0.f, 0.f);
    for (int i = tid; i < total; i += 256){
        int s = (i < deg) ? col[rp0 + i] : n;
        float4 ev = *(const float4*)(es + (size_t)s * HEADS);
        sm.x += expf(lrelu(ev.x + edv.x) - m4.x);
        sm.y += expf(lrelu(ev.y + edv.y) - m4.y);
        sm.z += expf(lrelu(ev.z + edv.z) - m4.z);
        sm.w += expf(lrelu(ev.w + edv.w) - m4.w);
    }
    for (int off = 32; off > 0; off >>= 1){
        sm.x += __shfl_down(sm.x, off);
        sm.y += __shfl_down(sm.y, off);
        sm.z += __shfl_down(sm.z, off);
        sm.w += __shfl_down(sm.w, off);
    }
    if (lane == 0) sred[w] = sm;
    __syncthreads();
    if (tid == 0){
        float4 a = sred[0], b = sred[1], c = sred[2], d = sred[3];
        a.x += b.x + c.x + d.x;
        a.y += b.y + c.y + d.y;
        a.z += b.z + c.z + d.z;
        a.w += b.w + c.w + d.w;
        sbc = a;
    }
    __syncthreads();
    float4 s4 = sbc;

    float myM  = (w == 0) ? m4.x  : (w == 1) ? m4.y  : (w == 2) ? m4.z  : m4.w;
    float myS  = (w == 0) ? s4.x  : (w == 1) ? s4.y  : (w == 2) ? s4.z  : s4.w;
    float myEd = (w == 0) ? edv.x : (w == 1) ? edv.y : (w == 2) ? edv.z : edv.w;
    float myInv = 1.f / (myS + 1e-16f);
    int cidx = w * CPH + lane * 4;
    float4 acc = make_float4(0.f, 0.f, 0.f, 0.f);
    for (int i = 0; i < total; ++i){
        int s = (i < deg) ? col[rp0 + i] : n;
        float ei = es[(size_t)s * HEADS + w];
        float alpha = expf(lrelu(ei + myEd) - myM) * myInv;
        float4 hv = *(const float4*)(hsrc + (size_t)s * DHID + cidx);
        acc.x += alpha * hv.x;
        acc.y += alpha * hv.y;
        acc.z += alpha * hv.z;
        acc.w += alpha * hv.w;
    }
    float4 bv = *(const float4*)(bias + cidx);
    float4 o;
    o.x = eluf(acc.x + bv.x);
    o.y = eluf(acc.y + bv.y);
    o.z = eluf(acc.z + bv.z);
    o.w = eluf(acc.w + bv.w);
    *(float4*)(out + (size_t)n * DHID + cidx) = o;
}

// ---------------- per-graph mean/max pooling ----------------
__global__ __launch_bounds__(256) void k_pool(const float* __restrict__ hf, const int* __restrict__ lo,
                                              const int* __restrict__ hi, float* __restrict__ gfeat){
    int g = blockIdx.x;
    int tid = threadIdx.x;
    int l = lo[g], h2 = hi[g];
    int cntn = (h2 > l) ? (h2 - l) : 0;
    int c = tid * 4;
    float4 sum = make_float4(0.f, 0.f, 0.f, 0.f);
    float4 mx = make_float4(-FLT_BIG, -FLT_BIG, -FLT_BIG, -FLT_BIG);
    for (int i = l; i < h2; ++i){
        float4 v = *(const float4*)(hf + (size_t)i * DHID + c);
        sum.x += v.x; sum.y += v.y; sum.z += v.z; sum.w += v.w;
        mx.x = fmaxf(mx.x, v.x); mx.y = fmaxf(mx.y, v.y);
        mx.z = fmaxf(mx.z, v.z); mx.w = fmaxf(mx.w, v.w);
    }
    float invc = 1.f / (float)((cntn > 1) ? cntn : 1);
    float4 mean = make_float4(sum.x * invc, sum.y * invc, sum.z * invc, sum.w * invc);
    if (cntn == 0) mx = make_float4(0.f, 0.f, 0.f, 0.f);
    *(float4*)(gfeat + (size_t)g * 2048 + c)        = mean;
    *(float4*)(gfeat + (size_t)g * 2048 + 1024 + c) = mx;
}

// ---------------- small FC ----------------
__global__ __launch_bounds__(256) void k_fc(const float* __restrict__ X, const float* __restrict__ W,
                                            const float* __restrict__ b, float* __restrict__ Y,
                                            int K, int Nc, int relu){
    __shared__ float xr[2048];
    int r = blockIdx.y;
    int tid = threadIdx.x;
    for (int i = tid; i < K; i += 256) xr[i] = X[(size_t)r * K + i];
    __syncthreads();
    int c = blockIdx.x * 256 + tid;
    if (c >= Nc) return;
    float acc = b[c];
    for (int k = 0; k < K; ++k) acc += xr[k] * W[(size_t)k * Nc + c];
    if (relu) acc = fmaxf(acc, 0.f);
    Y[(size_t)r * Nc + c] = acc;
}

// ---------------- launch ----------------
extern "C" void kernel_launch(void* const* d_in, const int* in_sizes, int n_in,
                              void* d_out, int out_size, void* d_ws, size_t ws_size,
                              hipStream_t stream) {
    const float* x      = (const float*)d_in[0];
    const int*   ei     = (const int*)  d_in[1];
    const int*   batch  = (const int*)  d_in[2];
    const float* W1     = (const float*)d_in[3];
    const float* asrc1  = (const float*)d_in[4];
    const float* adst1  = (const float*)d_in[5];
    const float* b1     = (const float*)d_in[6];
    const float* W2     = (const float*)d_in[7];
    const float* asrc2  = (const float*)d_in[8];
    const float* adst2  = (const float*)d_in[9];
    const float* b2     = (const float*)d_in[10];
    const float* Wc1    = (const float*)d_in[11];
    const float* bc1    = (const float*)d_in[12];
    const float* Wc2    = (const float*)d_in[13];
    const float* bc2    = (const float*)d_in[14];
    const float* Wc3    = (const float*)d_in[15];
    const float* bc3    = (const float*)d_in[16];

    const int N = in_sizes[2];          // 50000
    const int E = in_sizes[1] / 2;      // 200000
    const int G = out_size / 5;         // 64
    const int DIN = in_sizes[0] / N;    // 768

    const int* srcI = ei;
    const int* dstI = ei + E;

    char* p = (char*)d_ws;
    auto alloc = [&](size_t bytes) -> void* {
        void* q = (void*)p;
        p += (bytes + 255) & ~(size_t)255;
        return q;
    };
    // two 205MB ping-pong regions
    char* R1 = (char*)alloc((size_t)N * DHID * 4);
    char* R2 = (char*)alloc((size_t)N * DHID * 4);
    float* es     = (float*)alloc((size_t)N * HEADS * 4);
    float* ed     = (float*)alloc((size_t)N * HEADS * 4);
    float* gfeat  = (float*)alloc((size_t)G * 2048 * 4);
    float* z1     = (float*)alloc((size_t)G * 512 * 4);
    float* z2     = (float*)alloc((size_t)G * 256 * 4);
    int*   cnt    = (int*)  alloc((size_t)N * 4);
    int*   fill   = (int*)  alloc((size_t)N * 4);
    int*   rowptr = (int*)  alloc((size_t)(N + 1) * 4);
    int*   col    = (int*)  alloc((size_t)E * 4);
    int*   lo     = (int*)  alloc((size_t)G * 4);
    int*   hi     = (int*)  alloc((size_t)G * 4);
    u16*   w1th   = (u16*)  alloc((size_t)DIN * DHID * 2);
    u16*   w1tl   = (u16*)  alloc((size_t)DIN * DHID * 2);
    u16*   w2th   = (u16*)  alloc((size_t)DHID * DHID * 2);
    u16*   w2tl   = (u16*)  alloc((size_t)DHID * DHID * 2);
    float* logits = (float*)d_out;

    int nb = (N + 255) / 256;
    int ebp = (E + 255) / 256;

    // CSR + pooling bounds
    k_init   <<<nb,  256, 0, stream>>>(cnt, fill, lo, hi, N, G);
    k_count  <<<ebp, 256, 0, stream>>>(dstI, cnt, E);
    k_scan   <<<1,  1024, 0, stream>>>(cnt, rowptr, N, E);
    k_scatter<<<ebp, 256, 0, stream>>>(srcI, dstI, rowptr, fill, col, E);
    k_bounds <<<nb,  256, 0, stream>>>(batch, lo, hi, N);

    // weight splits (with transpose)
    k_splitT<<<(DIN * DHID + 255) / 256, 256, 0, stream>>>(W1, w1th, w1tl, DIN, DHID);
    k_splitT<<<(DHID * DHID + 255) / 256, 256, 0, stream>>>(W2, w2th, w2tl, DHID, DHID);

    dim3 gemmGrd(DHID / 128, (N + 127) / 128);

    // ---- GAT layer 1: A = x (N x 768) in R1, h1 -> R2 ----
    u16* a1h = (u16*)R1;
    u16* a1l = a1h + (size_t)N * DIN;
    long L41 = (long)N * DIN / 4;
    k_split<<<(unsigned)((L41 + 255) / 256), 256, 0, stream>>>(x, a1h, a1l, L41);
    float* h1 = (float*)R2;
    k_gemm_mfma<<<gemmGrd, 256, 0, stream>>>(a1h, a1l, w1th, w1tl, h1, N, DIN, DHID);
    k_esd<<<N, 256, 0, stream>>>(h1, asrc1, adst1, es, ed);
    float* o1 = (float*)R1;
    k_agg<<<N, 256, 0, stream>>>(h1, es, ed, rowptr, col, b1, o1);

    // ---- GAT layer 2: split o1 (R1) -> R2, h2 -> R1, out -> R2 ----
    u16* a2h = (u16*)R2;
    u16* a2l = a2h + (size_t)N * DHID;
    long L42 = (long)N * DHID / 4;
    k_split<<<(unsigned)((L42 + 255) / 256), 256, 0, stream>>>(o1, a2h, a2l, L42);
    float* h2 = (float*)R1;
    k_gemm_mfma<<<gemmGrd, 256, 0, stream>>>(a2h, a2l, w2th, w2tl, h2, N, DHID, DHID);
    k_esd<<<N, 256, 0, stream>>>(h2, asrc2, adst2, es, ed);
    float* o2 = (float*)R2;
    k_agg<<<N, 256, 0, stream>>>(h2, es, ed, rowptr, col, b2, o2);

    // ---- pooling + classifier ----
    k_pool<<<G, 256, 0, stream>>>(o2, lo, hi, gfeat);
    k_fc<<<dim3(2, G), 256, 0, stream>>>(gfeat, Wc1, bc1, z1, 2048, 512, 1);
    k_fc<<<dim3(1, G), 256, 0, stream>>>(z1,    Wc2, bc2, z2, 512,  256, 1);
    k_fc<<<dim3(1, G), 256, 0, stream>>>(z2,    Wc3, bc3, logits, 256, 5, 0);
}

// Round 3
// 2216.952 us; speedup vs baseline: 1.8821x; 1.1387x over previous
//
#include <hip/hip_runtime.h>
#include <math.h>

#define HEADS 4
#define CPH 256
#define DHID 1024
#define NEG_SLOPE 0.2f
#define FLT_BIG 3.402823466e38f
#define PCHUNK 128

typedef unsigned short u16;
typedef __bf16 bf16x8 __attribute__((ext_vector_type(8)));
typedef float f32x4 __attribute__((ext_vector_type(4)));

__device__ __forceinline__ float lrelu(float x){ return x > 0.f ? x : NEG_SLOPE * x; }
__device__ __forceinline__ float eluf(float x){ return x > 0.f ? x : expf(x) - 1.f; }

// ---- fp32 -> bf16 split helpers (RNE) ----
__device__ __forceinline__ u16 f2bf(float f){
    unsigned u = __float_as_uint(f);
    u += 0x7fffu + ((u >> 16) & 1u);
    return (u16)(u >> 16);
}
__device__ __forceinline__ float bf2f(u16 h){ return __uint_as_float(((unsigned)h) << 16); }

__device__ __forceinline__ void gload_lds16(const void* g, void* l){
    __builtin_amdgcn_global_load_lds((const __attribute__((address_space(1))) unsigned int*)g,
                                     (__attribute__((address_space(3))) unsigned int*)l, 16, 0, 0);
}

// float atomic max via int/uint ordering trick (works for mixed signs)
__device__ __forceinline__ void atomicMaxF(float* addr, float v){
    if (v >= 0.f) atomicMax((int*)addr, __float_as_int(v));
    else          atomicMin((unsigned int*)addr, __float_as_uint(v));
}

// ---------------- CSR build + pooling bounds ----------------
__global__ void k_init(int* cnt, int* fill, int* lo, int* hi, int N, int G){
    int i = blockIdx.x * blockDim.x + threadIdx.x;
    if (i < N){ cnt[i] = 0; fill[i] = 0; }
    if (i < G){ lo[i] = 0x7fffffff; hi[i] = 0; }
}

__global__ void k_count(const int* __restrict__ dst, int* __restrict__ cnt, int E){
    int e = blockIdx.x * blockDim.x + threadIdx.x;
    if (e < E) atomicAdd(&cnt[dst[e]], 1);
}

__global__ __launch_bounds__(1024) void k_scan(const int* __restrict__ cnt, int* __restrict__ rowptr,
                                               int N, int E){
    __shared__ int tot[1024];
    int tid = threadIdx.x;
    int items = (N + 1023) >> 10;
    int base = tid * items;
    int sum = 0;
    for (int i = 0; i < items; ++i){ int idx = base + i; if (idx < N) sum += cnt[idx]; }
    tot[tid] = sum;
    __syncthreads();
    for (int off = 1; off < 1024; off <<= 1){
        int t = (tid >= off) ? tot[tid - off] : 0;
        __syncthreads();
        tot[tid] += t;
        __syncthreads();
    }
    int run = tot[tid] - sum;
    for (int i = 0; i < items; ++i){
        int idx = base + i;
        if (idx < N){ rowptr[idx] = run; run += cnt[idx]; }
    }
    if (tid == 0) rowptr[N] = E;
}

__global__ void k_scatter(const int* __restrict__ src, const int* __restrict__ dst,
                          const int* __restrict__ rowptr, int* __restrict__ fill,
                          int* __restrict__ col, int E){
    int e = blockIdx.x * blockDim.x + threadIdx.x;
    if (e < E){
        int d = dst[e];
        int pos = rowptr[d] + atomicAdd(&fill[d], 1);
        col[pos] = src[e];
    }
}

__global__ void k_bounds(const int* __restrict__ batch, int* lo, int* hi, int N){
    int i = blockIdx.x * blockDim.x + threadIdx.x;
    if (i < N){
        int b = batch[i];
        atomicMin(&lo[b], i);
        atomicMax(&hi[b], i + 1);
    }
}

// ---------------- split kernels: fp32 -> bf16 hi/lo ----------------
__global__ void k_split(const float* __restrict__ X, u16* __restrict__ hi, u16* __restrict__ lo, long L4){
    long i = (long)blockIdx.x * blockDim.x + threadIdx.x;
    if (i < L4){
        float4 v = ((const float4*)X)[i];
        ushort4 h, l;
        h.x = f2bf(v.x); l.x = f2bf(v.x - bf2f(h.x));
        h.y = f2bf(v.y); l.y = f2bf(v.y - bf2f(h.y));
        h.z = f2bf(v.z); l.z = f2bf(v.z - bf2f(h.z));
        h.w = f2bf(v.w); l.w = f2bf(v.w - bf2f(h.w));
        ((ushort4*)hi)[i] = h;
        ((ushort4*)lo)[i] = l;
    }
}

// W (KxN fp32, row-major) -> WT hi/lo (NxK bf16)
__global__ void k_splitT(const float* __restrict__ W, u16* __restrict__ hiT, u16* __restrict__ loT,
                         int K, int Nn){
    int idx = blockIdx.x * blockDim.x + threadIdx.x;
    if (idx < K * Nn){
        int k = idx / Nn, n = idx - k * Nn;
        float v = W[idx];
        u16 h = f2bf(v);
        hiT[(size_t)n * K + k] = h;
        loT[(size_t)n * K + k] = f2bf(v - bf2f(h));
    }
}

// ---------------- split-bf16 MFMA GEMM: C = A(MxK) @ BT(NxK)^T ----------------
__global__ __launch_bounds__(256) void k_gemm_mfma(
    const u16* __restrict__ Ahi, const u16* __restrict__ Alo,
    const u16* __restrict__ BThi, const u16* __restrict__ BTlo,
    float* __restrict__ C, int M, int K, int Nn)
{
    __shared__ __align__(16) u16 As[2][128][32];
    __shared__ __align__(16) u16 Bs[2][128][32];
    int tid = threadIdx.x;
    int w = tid >> 6, lane = tid & 63;
    int row0 = blockIdx.y * 128, col0 = blockIdx.x * 128;

    int srow = tid >> 2;
    int skoff = (tid & 3) * 8;

    int wm = (w >> 1) * 64, wn = (w & 1) * 64;
    int fr = lane & 15;
    int fq = lane >> 4;

    f32x4 acc[4][4];
#pragma unroll
    for (int i = 0; i < 4; ++i)
#pragma unroll
        for (int j = 0; j < 4; ++j){ acc[i][j].x = 0.f; acc[i][j].y = 0.f; acc[i][j].z = 0.f; acc[i][j].w = 0.f; }

    int ra0 = row0 + srow;      if (ra0 >= M) ra0 = M - 1;
    int ra1 = row0 + srow + 64; if (ra1 >= M) ra1 = M - 1;
    int rb0 = col0 + srow;
    int rb1 = col0 + srow + 64;

    for (int k0 = 0; k0 < K; k0 += 32){
        size_t ga0 = (size_t)ra0 * K + k0 + skoff;
        size_t ga1 = (size_t)ra1 * K + k0 + skoff;
        size_t gb0 = (size_t)rb0 * K + k0 + skoff;
        size_t gb1 = (size_t)rb1 * K + k0 + skoff;
        gload_lds16(Ahi  + ga0, &As[0][srow     ][skoff]);
        gload_lds16(Ahi  + ga1, &As[0][srow + 64][skoff]);
        gload_lds16(Alo  + ga0, &As[1][srow     ][skoff]);
        gload_lds16(Alo  + ga1, &As[1][srow + 64][skoff]);
        gload_lds16(BThi + gb0, &Bs[0][srow     ][skoff]);
        gload_lds16(BThi + gb1, &Bs[0][srow + 64][skoff]);
        gload_lds16(BTlo + gb0, &Bs[1][srow     ][skoff]);
        gload_lds16(BTlo + gb1, &Bs[1][srow + 64][skoff]);
        __syncthreads();

        bf16x8 ah[4], al[4], bh[4], bl[4];
#pragma unroll
        for (int i = 0; i < 4; ++i){
            ah[i] = *(const bf16x8*)&As[0][wm + i * 16 + fr][fq * 8];
            al[i] = *(const bf16x8*)&As[1][wm + i * 16 + fr][fq * 8];
            bh[i] = *(const bf16x8*)&Bs[0][wn + i * 16 + fr][fq * 8];
            bl[i] = *(const bf16x8*)&Bs[1][wn + i * 16 + fr][fq * 8];
        }
#pragma unroll
        for (int i = 0; i < 4; ++i)
#pragma unroll
            for (int j = 0; j < 4; ++j){
                acc[i][j] = __builtin_amdgcn_mfma_f32_16x16x32_bf16(ah[i], bh[j], acc[i][j], 0, 0, 0);
                acc[i][j] = __builtin_amdgcn_mfma_f32_16x16x32_bf16(ah[i], bl[j], acc[i][j], 0, 0, 0);
                acc[i][j] = __builtin_amdgcn_mfma_f32_16x16x32_bf16(al[i], bh[j], acc[i][j], 0, 0, 0);
            }
        __syncthreads();
    }

#pragma unroll
    for (int i = 0; i < 4; ++i){
#pragma unroll
        for (int j = 0; j < 4; ++j){
            int col = col0 + wn + j * 16 + fr;
#pragma unroll
            for (int r = 0; r < 4; ++r){
                int row = row0 + wm + i * 16 + fq * 4 + r;
                if (row < M) C[(size_t)row * Nn + col] = acc[i][j][r];
            }
        }
    }
}

// ---------------- per-node attention score dots ----------------
__global__ __launch_bounds__(256) void k_esd(const float* __restrict__ h, const float* __restrict__ asrc,
                                             const float* __restrict__ adst,
                                             float* __restrict__ es, float* __restrict__ ed){
    int n = blockIdx.x;
    int tid = threadIdx.x;
    int w = tid >> 6, lane = tid & 63;
    const float4* hp = (const float4*)(h + (size_t)n * DHID + w * CPH);
    const float4* ap = (const float4*)(asrc + w * CPH);
    const float4* dp = (const float4*)(adst + w * CPH);
    float4 hv = hp[lane], av = ap[lane], dv = dp[lane];
    float s = hv.x * av.x + hv.y * av.y + hv.z * av.z + hv.w * av.w;
    float d = hv.x * dv.x + hv.y * dv.y + hv.z * dv.z + hv.w * dv.w;
    for (int off = 32; off > 0; off >>= 1){
        s += __shfl_down(s, off);
        d += __shfl_down(d, off);
    }
    if (lane == 0){ es[n * HEADS + w] = s; ed[n * HEADS + w] = d; }
}

// ---------------- per-dst-node segment softmax + aggregation + bias + elu ----------------
__global__ __launch_bounds__(256) void k_agg(const float* __restrict__ hsrc, const float* __restrict__ es,
                                             const float* __restrict__ ed, const int* __restrict__ rowptr,
                                             const int* __restrict__ col, const float* __restrict__ bias,
                                             float* __restrict__ out){
    int n = blockIdx.x;
    int tid = threadIdx.x;
    int w = tid >> 6, lane = tid & 63;
    int rp0 = rowptr[n];
    int deg = rowptr[n + 1] - rp0;
    int total = deg + 1;
    float4 edv = *(const float4*)(ed + (size_t)n * HEADS);

    __shared__ float4 sred[4];
    __shared__ float4 sbc;

    float4 mx = make_float4(-FLT_BIG, -FLT_BIG, -FLT_BIG, -FLT_BIG);
    for (int i = tid; i < total; i += 256){
        int s = (i < deg) ? col[rp0 + i] : n;
        float4 ev = *(const float4*)(es + (size_t)s * HEADS);
        mx.x = fmaxf(mx.x, lrelu(ev.x + edv.x));
        mx.y = fmaxf(mx.y, lrelu(ev.y + edv.y));
        mx.z = fmaxf(mx.z, lrelu(ev.z + edv.z));
        mx.w = fmaxf(mx.w, lrelu(ev.w + edv.w));
    }
    for (int off = 32; off > 0; off >>= 1){
        mx.x = fmaxf(mx.x, __shfl_down(mx.x, off));
        mx.y = fmaxf(mx.y, __shfl_down(mx.y, off));
        mx.z = fmaxf(mx.z, __shfl_down(mx.z, off));
        mx.w = fmaxf(mx.w, __shfl_down(mx.w, off));
    }
    if (lane == 0) sred[w] = mx;
    __syncthreads();
    if (tid == 0){
        float4 a = sred[0], b = sred[1], c = sred[2], d = sred[3];
        a.x = fmaxf(fmaxf(a.x, b.x), fmaxf(c.x, d.x));
        a.y = fmaxf(fmaxf(a.y, b.y), fmaxf(c.y, d.y));
        a.z = fmaxf(fmaxf(a.z, b.z), fmaxf(c.z, d.z));
        a.w = fmaxf(fmaxf(a.w, b.w), fmaxf(c.w, d.w));
        sbc = a;
    }
    __syncthreads();
    float4 m4 = sbc;

    float4 sm = make_float4(0.f, 0.f, 0.f, 0.f);
    for (int i = tid; i < total; i += 256){
        int s = (i < deg) ? col[rp0 + i] : n;
        float4 ev = *(const float4*)(es + (size_t)s * HEADS);
        sm.x += expf(lrelu(ev.x + edv.x) - m4.x);
        sm.y += expf(lrelu(ev.y + edv.y) - m4.y);
        sm.z += expf(lrelu(ev.z + edv.z) - m4.z);
        sm.w += expf(lrelu(ev.w + edv.w) - m4.w);
    }
    for (int off = 32; off > 0; off >>= 1){
        sm.x += __shfl_down(sm.x, off);
        sm.y += __shfl_down(sm.y, off);
        sm.z += __shfl_down(sm.z, off);
        sm.w += __shfl_down(sm.w, off);
    }
    if (lane == 0) sred[w] = sm;
    __syncthreads();
    if (tid == 0){
        float4 a = sred[0], b = sred[1], c = sred[2], d = sred[3];
        a.x += b.x + c.x + d.x;
        a.y += b.y + c.y + d.y;
        a.z += b.z + c.z + d.z;
        a.w += b.w + c.w + d.w;
        sbc = a;
    }
    __syncthreads();
    float4 s4 = sbc;

    float myM  = (w == 0) ? m4.x  : (w == 1) ? m4.y  : (w == 2) ? m4.z  : m4.w;
    float myS  = (w == 0) ? s4.x  : (w == 1) ? s4.y  : (w == 2) ? s4.z  : s4.w;
    float myEd = (w == 0) ? edv.x : (w == 1) ? edv.y : (w == 2) ? edv.z : edv.w;
    float myInv = 1.f / (myS + 1e-16f);
    int cidx = w * CPH + lane * 4;
    float4 acc = make_float4(0.f, 0.f, 0.f, 0.f);
    for (int i = 0; i < total; ++i){
        int s = (i < deg) ? col[rp0 + i] : n;
        float ei = es[(size_t)s * HEADS + w];
        float alpha = expf(lrelu(ei + myEd) - myM) * myInv;
        float4 hv = *(const float4*)(hsrc + (size_t)s * DHID + cidx);
        acc.x += alpha * hv.x;
        acc.y += alpha * hv.y;
        acc.z += alpha * hv.z;
        acc.w += alpha * hv.w;
    }
    float4 bv = *(const float4*)(bias + cidx);
    float4 o;
    o.x = eluf(acc.x + bv.x);
    o.y = eluf(acc.y + bv.y);
    o.z = eluf(acc.z + bv.z);
    o.w = eluf(acc.w + bv.w);
    *(float4*)(out + (size_t)n * DHID + cidx) = o;
}

// ---------------- two-stage per-graph mean/max pooling ----------------
__global__ __launch_bounds__(256) void k_pool_init(float* __restrict__ gsum, float* __restrict__ gmax, int L){
    int i = blockIdx.x * blockDim.x + threadIdx.x;
    if (i < L){ gsum[i] = 0.f; gmax[i] = -FLT_BIG; }
}

// grid: (ceil(N/PCHUNK), DHID/256); block 256. Thread owns one channel, streams PCHUNK rows.
__global__ __launch_bounds__(256) void k_pool_partial(const float* __restrict__ hf,
                                                      const int* __restrict__ batch,
                                                      float* __restrict__ gsum, float* __restrict__ gmax,
                                                      int N){
    int c = blockIdx.y * 256 + threadIdx.x;
    int i0 = blockIdx.x * PCHUNK;
    int i1 = i0 + PCHUNK; if (i1 > N) i1 = N;
    int curg = batch[i0];
    float s = 0.f, m = -FLT_BIG;
    for (int i = i0; i < i1; ++i){
        int g = batch[i];            // block-uniform broadcast load
        if (g != curg){
            atomicAdd(&gsum[(size_t)curg * DHID + c], s);
            atomicMaxF(&gmax[(size_t)curg * DHID + c], m);
            s = 0.f; m = -FLT_BIG; curg = g;
        }
        float v = hf[(size_t)i * DHID + c];
        s += v;
        m = fmaxf(m, v);
    }
    atomicAdd(&gsum[(size_t)curg * DHID + c], s);
    atomicMaxF(&gmax[(size_t)curg * DHID + c], m);
}

__global__ __launch_bounds__(256) void k_pool_final(const float* __restrict__ gsum,
                                                    const float* __restrict__ gmax,
                                                    const int* __restrict__ lo, const int* __restrict__ hi,
                                                    float* __restrict__ gfeat){
    int g = blockIdx.x;
    int c = threadIdx.x * 4;
    int l = lo[g], h2 = hi[g];
    int cnt = (h2 > l) ? (h2 - l) : 0;
    float invc = 1.f / (float)((cnt > 1) ? cnt : 1);
    float4 s = *(const float4*)(gsum + (size_t)g * DHID + c);
    float4 m = *(const float4*)(gmax + (size_t)g * DHID + c);
    float4 mean = make_float4(s.x * invc, s.y * invc, s.z * invc, s.w * invc);
    if (cnt == 0) m = make_float4(0.f, 0.f, 0.f, 0.f);
    *(float4*)(gfeat + (size_t)g * 2048 + c)        = mean;
    *(float4*)(gfeat + (size_t)g * 2048 + 1024 + c) = m;
}

// ---------------- small FC ----------------
__global__ __launch_bounds__(256) void k_fc(const float* __restrict__ X, const float* __restrict__ W,
                                            const float* __restrict__ b, float* __restrict__ Y,
                                            int K, int Nc, int relu){
    __shared__ float xr[2048];
    int r = blockIdx.y;
    int tid = threadIdx.x;
    for (int i = tid; i < K; i += 256) xr[i] = X[(size_t)r * K + i];
    __syncthreads();
    int c = blockIdx.x * 256 + tid;
    if (c >= Nc) return;
    float acc = b[c];
    for (int k = 0; k < K; ++k) acc += xr[k] * W[(size_t)k * Nc + c];
    if (relu) acc = fmaxf(acc, 0.f);
    Y[(size_t)r * Nc + c] = acc;
}

// ---------------- launch ----------------
extern "C" void kernel_launch(void* const* d_in, const int* in_sizes, int n_in,
                              void* d_out, int out_size, void* d_ws, size_t ws_size,
                              hipStream_t stream) {
    const float* x      = (const float*)d_in[0];
    const int*   ei     = (const int*)  d_in[1];
    const int*   batch  = (const int*)  d_in[2];
    const float* W1     = (const float*)d_in[3];
    const float* asrc1  = (const float*)d_in[4];
    const float* adst1  = (const float*)d_in[5];
    const float* b1     = (const float*)d_in[6];
    const float* W2     = (const float*)d_in[7];
    const float* asrc2  = (const float*)d_in[8];
    const float* adst2  = (const float*)d_in[9];
    const float* b2     = (const float*)d_in[10];
    const float* Wc1    = (const float*)d_in[11];
    const float* bc1    = (const float*)d_in[12];
    const float* Wc2    = (const float*)d_in[13];
    const float* bc2    = (const float*)d_in[14];
    const float* Wc3    = (const float*)d_in[15];
    const float* bc3    = (const float*)d_in[16];

    const int N = in_sizes[2];
    const int E = in_sizes[1] / 2;
    const int G = out_size / 5;
    const int DIN = in_sizes[0] / N;

    const int* srcI = ei;
    const int* dstI = ei + E;

    char* p = (char*)d_ws;
    auto alloc = [&](size_t bytes) -> void* {
        void* q = (void*)p;
        p += (bytes + 255) & ~(size_t)255;
        return q;
    };
    char* R1 = (char*)alloc((size_t)N * DHID * 4);
    char* R2 = (char*)alloc((size_t)N * DHID * 4);
    float* es     = (float*)alloc((size_t)N * HEADS * 4);
    float* ed     = (float*)alloc((size_t)N * HEADS * 4);
    float* gfeat  = (float*)alloc((size_t)G * 2048 * 4);
    float* gsum   = (float*)alloc((size_t)G * DHID * 4);
    float* gmax   = (float*)alloc((size_t)G * DHID * 4);
    float* z1     = (float*)alloc((size_t)G * 512 * 4);
    float* z2     = (float*)alloc((size_t)G * 256 * 4);
    int*   cnt    = (int*)  alloc((size_t)N * 4);
    int*   fill   = (int*)  alloc((size_t)N * 4);
    int*   rowptr = (int*)  alloc((size_t)(N + 1) * 4);
    int*   col    = (int*)  alloc((size_t)E * 4);
    int*   lo     = (int*)  alloc((size_t)G * 4);
    int*   hi     = (int*)  alloc((size_t)G * 4);
    u16*   w1th   = (u16*)  alloc((size_t)DIN * DHID * 2);
    u16*   w1tl   = (u16*)  alloc((size_t)DIN * DHID * 2);
    u16*   w2th   = (u16*)  alloc((size_t)DHID * DHID * 2);
    u16*   w2tl   = (u16*)  alloc((size_t)DHID * DHID * 2);
    float* logits = (float*)d_out;

    int nb = (N + 255) / 256;
    int ebp = (E + 255) / 256;

    // CSR + pooling bounds
    k_init   <<<nb,  256, 0, stream>>>(cnt, fill, lo, hi, N, G);
    k_count  <<<ebp, 256, 0, stream>>>(dstI, cnt, E);
    k_scan   <<<1,  1024, 0, stream>>>(cnt, rowptr, N, E);
    k_scatter<<<ebp, 256, 0, stream>>>(srcI, dstI, rowptr, fill, col, E);
    k_bounds <<<nb,  256, 0, stream>>>(batch, lo, hi, N);

    // weight splits (with transpose)
    k_splitT<<<(DIN * DHID + 255) / 256, 256, 0, stream>>>(W1, w1th, w1tl, DIN, DHID);
    k_splitT<<<(DHID * DHID + 255) / 256, 256, 0, stream>>>(W2, w2th, w2tl, DHID, DHID);

    dim3 gemmGrd(DHID / 128, (N + 127) / 128);

    // ---- GAT layer 1 ----
    u16* a1h = (u16*)R1;
    u16* a1l = a1h + (size_t)N * DIN;
    long L41 = (long)N * DIN / 4;
    k_split<<<(unsigned)((L41 + 255) / 256), 256, 0, stream>>>(x, a1h, a1l, L41);
    float* h1 = (float*)R2;
    k_gemm_mfma<<<gemmGrd, 256, 0, stream>>>(a1h, a1l, w1th, w1tl, h1, N, DIN, DHID);
    k_esd<<<N, 256, 0, stream>>>(h1, asrc1, adst1, es, ed);
    float* o1 = (float*)R1;
    k_agg<<<N, 256, 0, stream>>>(h1, es, ed, rowptr, col, b1, o1);

    // ---- GAT layer 2 ----
    u16* a2h = (u16*)R2;
    u16* a2l = a2h + (size_t)N * DHID;
    long L42 = (long)N * DHID / 4;
    k_split<<<(unsigned)((L42 + 255) / 256), 256, 0, stream>>>(o1, a2h, a2l, L42);
    float* h2 = (float*)R1;
    k_gemm_mfma<<<gemmGrd, 256, 0, stream>>>(a2h, a2l, w2th, w2tl, h2, N, DHID, DHID);
    k_esd<<<N, 256, 0, stream>>>(h2, asrc2, adst2, es, ed);
    float* o2 = (float*)R2;
    k_agg<<<N, 256, 0, stream>>>(h2, es, ed, rowptr, col, b2, o2);

    // ---- pooling + classifier ----
    k_pool_init<<<(G * DHID + 255) / 256, 256, 0, stream>>>(gsum, gmax, G * DHID);
    dim3 poolGrd((N + PCHUNK - 1) / PCHUNK, DHID / 256);
    k_pool_partial<<<poolGrd, 256, 0, stream>>>(o2, batch, gsum, gmax, N);
    k_pool_final<<<G, 256, 0, stream>>>(gsum, gmax, lo, hi, gfeat);

    k_fc<<<dim3(2, G), 256, 0, stream>>>(gfeat, Wc1, bc1, z1, 2048, 512, 1);
    k_fc<<<dim3(1, G), 256, 0, stream>>>(z1,    Wc2, bc2, z2, 512,  256, 1);
    k_fc<<<dim3(1, G), 256, 0, stream>>>(z2,    Wc3, bc3, logits, 256, 5, 0);
}

// Round 4
// 2191.552 us; speedup vs baseline: 1.9039x; 1.0116x over previous
//
#include <hip/hip_runtime.h>
#include <math.h>

#define HEADS 4
#define CPH 256
#define DHID 1024
#define NEG_SLOPE 0.2f
#define FLT_BIG 3.402823466e38f
#define PCHUNK 128

typedef unsigned short u16;
typedef __bf16 bf16x8 __attribute__((ext_vector_type(8)));
typedef float f32x4 __attribute__((ext_vector_type(4)));

__device__ __forceinline__ float lrelu(float x){ return x > 0.f ? x : NEG_SLOPE * x; }
__device__ __forceinline__ float eluf(float x){ return x > 0.f ? x : expf(x) - 1.f; }

__device__ __forceinline__ u16 f2bf(float f){
    unsigned u = __float_as_uint(f);
    u += 0x7fffu + ((u >> 16) & 1u);
    return (u16)(u >> 16);
}
__device__ __forceinline__ float bf2f(u16 h){ return __uint_as_float(((unsigned)h) << 16); }
__device__ __forceinline__ float4 bf4_to_f4(ushort4 u){
    return make_float4(bf2f(u.x), bf2f(u.y), bf2f(u.z), bf2f(u.w));
}

__device__ __forceinline__ void gload_lds16(const void* g, void* l){
    __builtin_amdgcn_global_load_lds((const __attribute__((address_space(1))) unsigned int*)g,
                                     (__attribute__((address_space(3))) unsigned int*)l, 16, 0, 0);
}

__device__ __forceinline__ void atomicMaxF(float* addr, float v){
    if (v >= 0.f) atomicMax((int*)addr, __float_as_int(v));
    else          atomicMin((unsigned int*)addr, __float_as_uint(v));
}

// ---------------- CSR build + pooling bounds ----------------
__global__ void k_init(int* cnt, int* fill, int* lo, int* hi, int N, int G){
    int i = blockIdx.x * blockDim.x + threadIdx.x;
    if (i < N){ cnt[i] = 0; fill[i] = 0; }
    if (i < G){ lo[i] = 0x7fffffff; hi[i] = 0; }
}

__global__ void k_zeroes(float* es, float* ed, int N4){
    int i = blockIdx.x * blockDim.x + threadIdx.x;
    if (i < N4){ es[i] = 0.f; ed[i] = 0.f; }
}

__global__ void k_count(const int* __restrict__ dst, int* __restrict__ cnt, int E){
    int e = blockIdx.x * blockDim.x + threadIdx.x;
    if (e < E) atomicAdd(&cnt[dst[e]], 1);
}

__global__ __launch_bounds__(1024) void k_scan(const int* __restrict__ cnt, int* __restrict__ rowptr,
                                               int N, int E){
    __shared__ int tot[1024];
    int tid = threadIdx.x;
    int items = (N + 1023) >> 10;
    int base = tid * items;
    int sum = 0;
    for (int i = 0; i < items; ++i){ int idx = base + i; if (idx < N) sum += cnt[idx]; }
    tot[tid] = sum;
    __syncthreads();
    for (int off = 1; off < 1024; off <<= 1){
        int t = (tid >= off) ? tot[tid - off] : 0;
        __syncthreads();
        tot[tid] += t;
        __syncthreads();
    }
    int run = tot[tid] - sum;
    for (int i = 0; i < items; ++i){
        int idx = base + i;
        if (idx < N){ rowptr[idx] = run; run += cnt[idx]; }
    }
    if (tid == 0) rowptr[N] = E;
}

__global__ void k_scatter(const int* __restrict__ src, const int* __restrict__ dst,
                          const int* __restrict__ rowptr, int* __restrict__ fill,
                          int* __restrict__ col, int E){
    int e = blockIdx.x * blockDim.x + threadIdx.x;
    if (e < E){
        int d = dst[e];
        int pos = rowptr[d] + atomicAdd(&fill[d], 1);
        col[pos] = src[e];
    }
}

__global__ void k_bounds(const int* __restrict__ batch, int* lo, int* hi, int N){
    int i = blockIdx.x * blockDim.x + threadIdx.x;
    if (i < N){
        int b = batch[i];
        atomicMin(&lo[b], i);
        atomicMax(&hi[b], i + 1);
    }
}

// ---------------- split kernels ----------------
__global__ void k_split(const float* __restrict__ X, u16* __restrict__ hi, u16* __restrict__ lo, long L4){
    long i = (long)blockIdx.x * blockDim.x + threadIdx.x;
    if (i < L4){
        float4 v = ((const float4*)X)[i];
        ushort4 h, l;
        h.x = f2bf(v.x); l.x = f2bf(v.x - bf2f(h.x));
        h.y = f2bf(v.y); l.y = f2bf(v.y - bf2f(h.y));
        h.z = f2bf(v.z); l.z = f2bf(v.z - bf2f(h.z));
        h.w = f2bf(v.w); l.w = f2bf(v.w - bf2f(h.w));
        ((ushort4*)hi)[i] = h;
        ((ushort4*)lo)[i] = l;
    }
}

__global__ void k_splitT(const float* __restrict__ W, u16* __restrict__ hiT, u16* __restrict__ loT,
                         int K, int Nn){
    int idx = blockIdx.x * blockDim.x + threadIdx.x;
    if (idx < K * Nn){
        int k = idx / Nn, n = idx - k * Nn;
        float v = W[idx];
        u16 h = f2bf(v);
        hiT[(size_t)n * K + k] = h;
        loT[(size_t)n * K + k] = f2bf(v - bf2f(h));
    }
}

// ---------------- split-bf16 MFMA GEMM + fused e_src/e_dst, bf16 C ----------------
// C = A(MxK) @ BT(NxK)^T (3-product split, fp32 acc). Epilogue:
//   es[row][head] += sum_c C[row][c]*asrc[c], ed likewise (block's 128 cols = one head)
//   C stored as bf16.
// XCD swizzle: 8 col-blocks sharing an A-row-tile get linear ids with equal %8.
__global__ __launch_bounds__(256) void k_gemm_mfma(
    const u16* __restrict__ Ahi, const u16* __restrict__ Alo,
    const u16* __restrict__ BThi, const u16* __restrict__ BTlo,
    u16* __restrict__ Cbf, float* __restrict__ es, float* __restrict__ ed,
    const float* __restrict__ asrc, const float* __restrict__ adst,
    int M, int K, int Nn, int Rchunk)
{
    __shared__ __align__(16) u16 As[2][128][32];
    __shared__ __align__(16) u16 Bs[2][128][32];
    int tid = threadIdx.x;
    int w = tid >> 6, lane = tid & 63;

    // swizzle: y-rows partitioned into 8 contiguous chunks, one per XCD (%8 heuristic)
    int R = (M + 127) >> 7;
    int by = blockIdx.x * Rchunk + (blockIdx.y >> 3);   // gridDim.x==8
    int bx = blockIdx.y & 7;
    if (by >= R) return;
    int row0 = by * 128, col0 = bx * 128;

    int srow = tid >> 2;
    int skoff = (tid & 3) * 8;

    int wm = (w >> 1) * 64, wn = (w & 1) * 64;
    int fr = lane & 15;
    int fq = lane >> 4;

    f32x4 acc[4][4];
#pragma unroll
    for (int i = 0; i < 4; ++i)
#pragma unroll
        for (int j = 0; j < 4; ++j){ acc[i][j].x = 0.f; acc[i][j].y = 0.f; acc[i][j].z = 0.f; acc[i][j].w = 0.f; }

    int ra0 = row0 + srow;      if (ra0 >= M) ra0 = M - 1;
    int ra1 = row0 + srow + 64; if (ra1 >= M) ra1 = M - 1;
    int rb0 = col0 + srow;
    int rb1 = col0 + srow + 64;

    for (int k0 = 0; k0 < K; k0 += 32){
        size_t ga0 = (size_t)ra0 * K + k0 + skoff;
        size_t ga1 = (size_t)ra1 * K + k0 + skoff;
        size_t gb0 = (size_t)rb0 * K + k0 + skoff;
        size_t gb1 = (size_t)rb1 * K + k0 + skoff;
        gload_lds16(Ahi  + ga0, &As[0][srow     ][skoff]);
        gload_lds16(Ahi  + ga1, &As[0][srow + 64][skoff]);
        gload_lds16(Alo  + ga0, &As[1][srow     ][skoff]);
        gload_lds16(Alo  + ga1, &As[1][srow + 64][skoff]);
        gload_lds16(BThi + gb0, &Bs[0][srow     ][skoff]);
        gload_lds16(BThi + gb1, &Bs[0][srow + 64][skoff]);
        gload_lds16(BTlo + gb0, &Bs[1][srow     ][skoff]);
        gload_lds16(BTlo + gb1, &Bs[1][srow + 64][skoff]);
        __syncthreads();

        bf16x8 ah[4], al[4], bh[4], bl[4];
#pragma unroll
        for (int i = 0; i < 4; ++i){
            ah[i] = *(const bf16x8*)&As[0][wm + i * 16 + fr][fq * 8];
            al[i] = *(const bf16x8*)&As[1][wm + i * 16 + fr][fq * 8];
            bh[i] = *(const bf16x8*)&Bs[0][wn + i * 16 + fr][fq * 8];
            bl[i] = *(const bf16x8*)&Bs[1][wn + i * 16 + fr][fq * 8];
        }
#pragma unroll
        for (int i = 0; i < 4; ++i)
#pragma unroll
            for (int j = 0; j < 4; ++j){
                acc[i][j] = __builtin_amdgcn_mfma_f32_16x16x32_bf16(ah[i], bh[j], acc[i][j], 0, 0, 0);
                acc[i][j] = __builtin_amdgcn_mfma_f32_16x16x32_bf16(ah[i], bl[j], acc[i][j], 0, 0, 0);
                acc[i][j] = __builtin_amdgcn_mfma_f32_16x16x32_bf16(al[i], bh[j], acc[i][j], 0, 0, 0);
            }
        __syncthreads();
    }

    // ---- fused attention-score partial dots (exact, from fp32 acc) ----
    int head = col0 >> 8;               // block's 128 cols lie in one head
    float asv[4], adv[4];
#pragma unroll
    for (int j = 0; j < 4; ++j){
        int c = col0 + wn + j * 16 + fr;
        asv[j] = asrc[c];
        adv[j] = adst[c];
    }
#pragma unroll
    for (int i = 0; i < 4; ++i){
#pragma unroll
        for (int r = 0; r < 4; ++r){
            float ps = 0.f, pd = 0.f;
#pragma unroll
            for (int j = 0; j < 4; ++j){
                float c = acc[i][j][r];
                ps = fmaf(c, asv[j], ps);
                pd = fmaf(c, adv[j], pd);
            }
#pragma unroll
            for (int off = 1; off < 16; off <<= 1){
                ps += __shfl_xor(ps, off);
                pd += __shfl_xor(pd, off);
            }
            int row = row0 + wm + i * 16 + fq * 4 + r;
            if (fr == 0 && row < M){
                atomicAdd(&es[row * HEADS + head], ps);
                atomicAdd(&ed[row * HEADS + head], pd);
            }
        }
    }

    // ---- bf16 C store ----
#pragma unroll
    for (int i = 0; i < 4; ++i){
#pragma unroll
        for (int j = 0; j < 4; ++j){
            int colc = col0 + wn + j * 16 + fr;
#pragma unroll
            for (int r = 0; r < 4; ++r){
                int row = row0 + wm + i * 16 + fq * 4 + r;
                if (row < M) Cbf[(size_t)row * Nn + colc] = f2bf(acc[i][j][r]);
            }
        }
    }
}

// ---------------- segment softmax + aggregation (bf16 gather) + bias + elu + split write ----------------
__global__ __launch_bounds__(256) void k_agg(const u16* __restrict__ hsrc, const float* __restrict__ es,
                                             const float* __restrict__ ed, const int* __restrict__ rowptr,
                                             const int* __restrict__ col, const float* __restrict__ bias,
                                             u16* __restrict__ outhi, u16* __restrict__ outlo, int writeLo){
    int n = blockIdx.x;
    int tid = threadIdx.x;
    int w = tid >> 6, lane = tid & 63;
    int rp0 = rowptr[n];
    int deg = rowptr[n + 1] - rp0;
    int total = deg + 1;
    float4 edv = *(const float4*)(ed + (size_t)n * HEADS);

    __shared__ float4 sred[4];
    __shared__ float4 sbc;

    float4 mx = make_float4(-FLT_BIG, -FLT_BIG, -FLT_BIG, -FLT_BIG);
    for (int i = tid; i < total; i += 256){
        int s = (i < deg) ? col[rp0 + i] : n;
        float4 ev = *(const float4*)(es + (size_t)s * HEADS);
        mx.x = fmaxf(mx.x, lrelu(ev.x + edv.x));
        mx.y = fmaxf(mx.y, lrelu(ev.y + edv.y));
        mx.z = fmaxf(mx.z, lrelu(ev.z + edv.z));
        mx.w = fmaxf(mx.w, lrelu(ev.w + edv.w));
    }
    for (int off = 32; off > 0; off >>= 1){
        mx.x = fmaxf(mx.x, __shfl_down(mx.x, off));
        mx.y = fmaxf(mx.y, __shfl_down(mx.y, off));
        mx.z = fmaxf(mx.z, __shfl_down(mx.z, off));
        mx.w = fmaxf(mx.w, __shfl_down(mx.w, off));
    }
    if (lane == 0) sred[w] = mx;
    __syncthreads();
    if (tid == 0){
        float4 a = sred[0], b = sred[1], c = sred[2], d = sred[3];
        a.x = fmaxf(fmaxf(a.x, b.x), fmaxf(c.x, d.x));
        a.y = fmaxf(fmaxf(a.y, b.y), fmaxf(c.y, d.y));
        a.z = fmaxf(fmaxf(a.z, b.z), fmaxf(c.z, d.z));
        a.w = fmaxf(fmaxf(a.w, b.w), fmaxf(c.w, d.w));
        sbc = a;
    }
    __syncthreads();
    float4 m4 = sbc;

    float4 sm = make_float4(0.f, 0.f, 0.f, 0.f);
    for (int i = tid; i < total; i += 256){
        int s = (i < deg) ? col[rp0 + i] : n;
        float4 ev = *(const float4*)(es + (size_t)s * HEADS);
        sm.x += expf(lrelu(ev.x + edv.x) - m4.x);
        sm.y += expf(lrelu(ev.y + edv.y) - m4.y);
        sm.z += expf(lrelu(ev.z + edv.z) - m4.z);
        sm.w += expf(lrelu(ev.w + edv.w) - m4.w);
    }
    for (int off = 32; off > 0; off >>= 1){
        sm.x += __shfl_down(sm.x, off);
        sm.y += __shfl_down(sm.y, off);
        sm.z += __shfl_down(sm.z, off);
        sm.w += __shfl_down(sm.w, off);
    }
    if (lane == 0) sred[w] = sm;
    __syncthreads();
    if (tid == 0){
        float4 a = sred[0], b = sred[1], c = sred[2], d = sred[3];
        a.x += b.x + c.x + d.x;
        a.y += b.y + c.y + d.y;
        a.z += b.z + c.z + d.z;
        a.w += b.w + c.w + d.w;
        sbc = a;
    }
    __syncthreads();
    float4 s4 = sbc;

    float myM  = (w == 0) ? m4.x  : (w == 1) ? m4.y  : (w == 2) ? m4.z  : m4.w;
    float myS  = (w == 0) ? s4.x  : (w == 1) ? s4.y  : (w == 2) ? s4.z  : s4.w;
    float myEd = (w == 0) ? edv.x : (w == 1) ? edv.y : (w == 2) ? edv.z : edv.w;
    float myInv = 1.f / (myS + 1e-16f);
    int cidx = w * CPH + lane * 4;
    float4 acc = make_float4(0.f, 0.f, 0.f, 0.f);
    for (int i = 0; i < total; ++i){
        int s = (i < deg) ? col[rp0 + i] : n;
        float ei = es[(size_t)s * HEADS + w];
        float alpha = expf(lrelu(ei + myEd) - myM) * myInv;
        float4 hv = bf4_to_f4(*(const ushort4*)(hsrc + (size_t)s * DHID + cidx));
        acc.x += alpha * hv.x;
        acc.y += alpha * hv.y;
        acc.z += alpha * hv.z;
        acc.w += alpha * hv.w;
    }
    float4 bv = *(const float4*)(bias + cidx);
    float ox = eluf(acc.x + bv.x);
    float oy = eluf(acc.y + bv.y);
    float oz = eluf(acc.z + bv.z);
    float ow = eluf(acc.w + bv.w);
    ushort4 h4;
    h4.x = f2bf(ox); h4.y = f2bf(oy); h4.z = f2bf(oz); h4.w = f2bf(ow);
    *(ushort4*)(outhi + (size_t)n * DHID + cidx) = h4;
    if (writeLo){
        ushort4 l4;
        l4.x = f2bf(ox - bf2f(h4.x));
        l4.y = f2bf(oy - bf2f(h4.y));
        l4.z = f2bf(oz - bf2f(h4.z));
        l4.w = f2bf(ow - bf2f(h4.w));
        *(ushort4*)(outlo + (size_t)n * DHID + cidx) = l4;
    }
}

// ---------------- two-stage per-graph mean/max pooling (bf16 input) ----------------
__global__ __launch_bounds__(256) void k_pool_init(float* __restrict__ gsum, float* __restrict__ gmax, int L){
    int i = blockIdx.x * blockDim.x + threadIdx.x;
    if (i < L){ gsum[i] = 0.f; gmax[i] = -FLT_BIG; }
}

__global__ __launch_bounds__(256) void k_pool_partial(const u16* __restrict__ hf,
                                                      const int* __restrict__ batch,
                                                      float* __restrict__ gsum, float* __restrict__ gmax,
                                                      int N){
    int c = blockIdx.y * 256 + threadIdx.x;
    int i0 = blockIdx.x * PCHUNK;
    int i1 = i0 + PCHUNK; if (i1 > N) i1 = N;
    int curg = batch[i0];
    float s = 0.f, m = -FLT_BIG;
    for (int i = i0; i < i1; ++i){
        int g = batch[i];
        if (g != curg){
            atomicAdd(&gsum[(size_t)curg * DHID + c], s);
            atomicMaxF(&gmax[(size_t)curg * DHID + c], m);
            s = 0.f; m = -FLT_BIG; curg = g;
        }
        float v = bf2f(hf[(size_t)i * DHID + c]);
        s += v;
        m = fmaxf(m, v);
    }
    atomicAdd(&gsum[(size_t)curg * DHID + c], s);
    atomicMaxF(&gmax[(size_t)curg * DHID + c], m);
}

__global__ __launch_bounds__(256) void k_pool_final(const float* __restrict__ gsum,
                                                    const float* __restrict__ gmax,
                                                    const int* __restrict__ lo, const int* __restrict__ hi,
                                                    float* __restrict__ gfeat){
    int g = blockIdx.x;
    int c = threadIdx.x * 4;
    int l = lo[g], h2 = hi[g];
    int cnt = (h2 > l) ? (h2 - l) : 0;
    float invc = 1.f / (float)((cnt > 1) ? cnt : 1);
    float4 s = *(const float4*)(gsum + (size_t)g * DHID + c);
    float4 m = *(const float4*)(gmax + (size_t)g * DHID + c);
    float4 mean = make_float4(s.x * invc, s.y * invc, s.z * invc, s.w * invc);
    if (cnt == 0) m = make_float4(0.f, 0.f, 0.f, 0.f);
    *(float4*)(gfeat + (size_t)g * 2048 + c)        = mean;
    *(float4*)(gfeat + (size_t)g * 2048 + 1024 + c) = m;
}

// ---------------- small FC ----------------
__global__ __launch_bounds__(256) void k_fc(const float* __restrict__ X, const float* __restrict__ W,
                                            const float* __restrict__ b, float* __restrict__ Y,
                                            int K, int Nc, int relu){
    __shared__ float xr[2048];
    int r = blockIdx.y;
    int tid = threadIdx.x;
    for (int i = tid; i < K; i += 256) xr[i] = X[(size_t)r * K + i];
    __syncthreads();
    int c = blockIdx.x * 256 + tid;
    if (c >= Nc) return;
    float acc = b[c];
    for (int k = 0; k < K; ++k) acc += xr[k] * W[(size_t)k * Nc + c];
    if (relu) acc = fmaxf(acc, 0.f);
    Y[(size_t)r * Nc + c] = acc;
}

// ---------------- launch ----------------
extern "C" void kernel_launch(void* const* d_in, const int* in_sizes, int n_in,
                              void* d_out, int out_size, void* d_ws, size_t ws_size,
                              hipStream_t stream) {
    const float* x      = (const float*)d_in[0];
    const int*   ei     = (const int*)  d_in[1];
    const int*   batch  = (const int*)  d_in[2];
    const float* W1     = (const float*)d_in[3];
    const float* asrc1  = (const float*)d_in[4];
    const float* adst1  = (const float*)d_in[5];
    const float* b1     = (const float*)d_in[6];
    const float* W2     = (const float*)d_in[7];
    const float* asrc2  = (const float*)d_in[8];
    const float* adst2  = (const float*)d_in[9];
    const float* b2     = (const float*)d_in[10];
    const float* Wc1    = (const float*)d_in[11];
    const float* bc1    = (const float*)d_in[12];
    const float* Wc2    = (const float*)d_in[13];
    const float* bc2    = (const float*)d_in[14];
    const float* Wc3    = (const float*)d_in[15];
    const float* bc3    = (const float*)d_in[16];

    const int N = in_sizes[2];
    const int E = in_sizes[1] / 2;
    const int G = out_size / 5;
    const int DIN = in_sizes[0] / N;

    const int* srcI = ei;
    const int* dstI = ei + E;

    char* p = (char*)d_ws;
    auto alloc = [&](size_t bytes) -> void* {
        void* q = (void*)p;
        p += (bytes + 255) & ~(size_t)255;
        return q;
    };
    // R1: activations hi+lo (205 MB), R2: bf16 h plane (102 MB)
    u16*   R1     = (u16*)alloc((size_t)N * DHID * 2 * 2);
    u16*   R2     = (u16*)alloc((size_t)N * DHID * 2);
    float* es     = (float*)alloc((size_t)N * HEADS * 4);
    float* ed     = (float*)alloc((size_t)N * HEADS * 4);
    float* gfeat  = (float*)alloc((size_t)G * 2048 * 4);
    float* gsum   = (float*)alloc((size_t)G * DHID * 4);
    float* gmax   = (float*)alloc((size_t)G * DHID * 4);
    float* z1     = (float*)alloc((size_t)G * 512 * 4);
    float* z2     = (float*)alloc((size_t)G * 256 * 4);
    int*   cnt    = (int*)  alloc((size_t)N * 4);
    int*   fill   = (int*)  alloc((size_t)N * 4);
    int*   rowptr = (int*)  alloc((size_t)(N + 1) * 4);
    int*   col    = (int*)  alloc((size_t)E * 4);
    int*   lo     = (int*)  alloc((size_t)G * 4);
    int*   hi     = (int*)  alloc((size_t)G * 4);
    u16*   w1th   = (u16*)  alloc((size_t)DIN * DHID * 2);
    u16*   w1tl   = (u16*)  alloc((size_t)DIN * DHID * 2);
    u16*   w2th   = (u16*)  alloc((size_t)DHID * DHID * 2);
    u16*   w2tl   = (u16*)  alloc((size_t)DHID * DHID * 2);
    float* logits = (float*)d_out;

    int nb = (N + 255) / 256;
    int ebp = (E + 255) / 256;
    int zb = (N * HEADS + 255) / 256;

    // CSR + pooling bounds
    k_init   <<<nb,  256, 0, stream>>>(cnt, fill, lo, hi, N, G);
    k_count  <<<ebp, 256, 0, stream>>>(dstI, cnt, E);
    k_scan   <<<1,  1024, 0, stream>>>(cnt, rowptr, N, E);
    k_scatter<<<ebp, 256, 0, stream>>>(srcI, dstI, rowptr, fill, col, E);
    k_bounds <<<nb,  256, 0, stream>>>(batch, lo, hi, N);

    // weight splits (with transpose)
    k_splitT<<<(DIN * DHID + 255) / 256, 256, 0, stream>>>(W1, w1th, w1tl, DIN, DHID);
    k_splitT<<<(DHID * DHID + 255) / 256, 256, 0, stream>>>(W2, w2th, w2tl, DHID, DHID);

    int R = (N + 127) / 128;
    int Rchunk = (R + 7) / 8;
    dim3 gemmGrd(8, 8 * Rchunk);   // swizzled: x=XCD chunk, y = (local row, col-block)

    // ---- GAT layer 1 ----
    u16* a1h = R1;
    u16* a1l = R1 + (size_t)N * DIN;
    long L41 = (long)N * DIN / 4;
    k_split<<<(unsigned)((L41 + 255) / 256), 256, 0, stream>>>(x, a1h, a1l, L41);
    u16* h1 = R2;
    k_zeroes<<<zb, 256, 0, stream>>>(es, ed, N * HEADS);
    k_gemm_mfma<<<gemmGrd, 256, 0, stream>>>(a1h, a1l, w1th, w1tl, h1, es, ed, asrc1, adst1,
                                             N, DIN, DHID, Rchunk);
    u16* o1h = R1;
    u16* o1l = R1 + (size_t)N * DHID;
    k_agg<<<N, 256, 0, stream>>>(h1, es, ed, rowptr, col, b1, o1h, o1l, 1);

    // ---- GAT layer 2 ----
    u16* h2 = R2;
    k_zeroes<<<zb, 256, 0, stream>>>(es, ed, N * HEADS);
    k_gemm_mfma<<<gemmGrd, 256, 0, stream>>>(o1h, o1l, w2th, w2tl, h2, es, ed, asrc2, adst2,
                                             N, DHID, DHID, Rchunk);
    u16* o2h = R1;   // o1 dead; hi plane only
    k_agg<<<N, 256, 0, stream>>>(h2, es, ed, rowptr, col, b2, o2h, (u16*)0, 0);

    // ---- pooling + classifier ----
    k_pool_init<<<(G * DHID + 255) / 256, 256, 0, stream>>>(gsum, gmax, G * DHID);
    dim3 poolGrd((N + PCHUNK - 1) / PCHUNK, DHID / 256);
    k_pool_partial<<<poolGrd, 256, 0, stream>>>(o2h, batch, gsum, gmax, N);
    k_pool_final<<<G, 256, 0, stream>>>(gsum, gmax, lo, hi, gfeat);

    k_fc<<<dim3(2, G), 256, 0, stream>>>(gfeat, Wc1, bc1, z1, 2048, 512, 1);
    k_fc<<<dim3(1, G), 256, 0, stream>>>(z1,    Wc2, bc2, z2, 512,  256, 1);
    k_fc<<<dim3(1, G), 256, 0, stream>>>(z2,    Wc3, bc3, logits, 256, 5, 0);
}

// Round 5
// 1998.707 us; speedup vs baseline: 2.0876x; 1.0965x over previous
//
#include <hip/hip_runtime.h>
#include <math.h>

#define HEADS 4
#define CPH 256
#define DHID 1024
#define NEG_SLOPE 0.2f
#define FLT_BIG 3.402823466e38f
#define PCHUNK 128

typedef unsigned short u16;
typedef __bf16 bf16x8 __attribute__((ext_vector_type(8)));
typedef float f32x4 __attribute__((ext_vector_type(4)));

__device__ __forceinline__ float lrelu(float x){ return x > 0.f ? x : NEG_SLOPE * x; }
__device__ __forceinline__ float eluf(float x){ return x > 0.f ? x : expf(x) - 1.f; }

__device__ __forceinline__ u16 f2bf(float f){
    unsigned u = __float_as_uint(f);
    u += 0x7fffu + ((u >> 16) & 1u);
    return (u16)(u >> 16);
}
__device__ __forceinline__ float bf2f(u16 h){ return __uint_as_float(((unsigned)h) << 16); }
__device__ __forceinline__ float4 bf4_to_f4(ushort4 u){
    return make_float4(bf2f(u.x), bf2f(u.y), bf2f(u.z), bf2f(u.w));
}

__device__ __forceinline__ void gload_lds16(const void* g, void* l){
    __builtin_amdgcn_global_load_lds((const __attribute__((address_space(1))) unsigned int*)g,
                                     (__attribute__((address_space(3))) unsigned int*)l, 16, 0, 0);
}

__device__ __forceinline__ void atomicMaxF(float* addr, float v){
    if (v >= 0.f) atomicMax((int*)addr, __float_as_int(v));
    else          atomicMin((unsigned int*)addr, __float_as_uint(v));
}

// ---------------- CSR build + pooling bounds ----------------
__global__ void k_init(int* cnt, int* fill, int* lo, int* hi, int N, int G){
    int i = blockIdx.x * blockDim.x + threadIdx.x;
    if (i < N){ cnt[i] = 0; fill[i] = 0; }
    if (i < G){ lo[i] = 0x7fffffff; hi[i] = 0; }
}

__global__ void k_count(const int* __restrict__ dst, int* __restrict__ cnt, int E){
    int e = blockIdx.x * blockDim.x + threadIdx.x;
    if (e < E) atomicAdd(&cnt[dst[e]], 1);
}

__global__ __launch_bounds__(1024) void k_scan(const int* __restrict__ cnt, int* __restrict__ rowptr,
                                               int N, int E){
    __shared__ int tot[1024];
    int tid = threadIdx.x;
    int items = (N + 1023) >> 10;
    int base = tid * items;
    int sum = 0;
    for (int i = 0; i < items; ++i){ int idx = base + i; if (idx < N) sum += cnt[idx]; }
    tot[tid] = sum;
    __syncthreads();
    for (int off = 1; off < 1024; off <<= 1){
        int t = (tid >= off) ? tot[tid - off] : 0;
        __syncthreads();
        tot[tid] += t;
        __syncthreads();
    }
    int run = tot[tid] - sum;
    for (int i = 0; i < items; ++i){
        int idx = base + i;
        if (idx < N){ rowptr[idx] = run; run += cnt[idx]; }
    }
    if (tid == 0) rowptr[N] = E;
}

__global__ void k_scatter(const int* __restrict__ src, const int* __restrict__ dst,
                          const int* __restrict__ rowptr, int* __restrict__ fill,
                          int* __restrict__ col, int E){
    int e = blockIdx.x * blockDim.x + threadIdx.x;
    if (e < E){
        int d = dst[e];
        int pos = rowptr[d] + atomicAdd(&fill[d], 1);
        col[pos] = src[e];
    }
}

__global__ void k_bounds(const int* __restrict__ batch, int* lo, int* hi, int N){
    int i = blockIdx.x * blockDim.x + threadIdx.x;
    if (i < N){
        int b = batch[i];
        atomicMin(&lo[b], i);
        atomicMax(&hi[b], i + 1);
    }
}

// ---------------- split kernels ----------------
__global__ void k_split(const float* __restrict__ X, u16* __restrict__ hi, u16* __restrict__ lo, long L4){
    long i = (long)blockIdx.x * blockDim.x + threadIdx.x;
    if (i < L4){
        float4 v = ((const float4*)X)[i];
        ushort4 h, l;
        h.x = f2bf(v.x); l.x = f2bf(v.x - bf2f(h.x));
        h.y = f2bf(v.y); l.y = f2bf(v.y - bf2f(h.y));
        h.z = f2bf(v.z); l.z = f2bf(v.z - bf2f(h.z));
        h.w = f2bf(v.w); l.w = f2bf(v.w - bf2f(h.w));
        ((ushort4*)hi)[i] = h;
        ((ushort4*)lo)[i] = l;
    }
}

__global__ void k_splitT(const float* __restrict__ W, u16* __restrict__ hiT, u16* __restrict__ loT,
                         int K, int Nn){
    int idx = blockIdx.x * blockDim.x + threadIdx.x;
    if (idx < K * Nn){
        int k = idx / Nn, n = idx - k * Nn;
        float v = W[idx];
        u16 h = f2bf(v);
        hiT[(size_t)n * K + k] = h;
        loT[(size_t)n * K + k] = f2bf(v - bf2f(h));
    }
}

// ---------------- split-bf16 MFMA GEMM, bf16 C store ----------------
// C = A(MxK) @ BT(NxK)^T (3-product split, fp32 acc), C stored bf16.
// XCD swizzle: linear-%8-equal blocks (one XCD under round-robin) share an A row chunk.
__global__ __launch_bounds__(256) void k_gemm_mfma(
    const u16* __restrict__ Ahi, const u16* __restrict__ Alo,
    const u16* __restrict__ BThi, const u16* __restrict__ BTlo,
    u16* __restrict__ Cbf, int M, int K, int Nn, int Rchunk)
{
    __shared__ __align__(16) u16 As[2][128][32];
    __shared__ __align__(16) u16 Bs[2][128][32];
    int tid = threadIdx.x;
    int w = tid >> 6, lane = tid & 63;

    int R = (M + 127) >> 7;
    int by = blockIdx.x * Rchunk + (blockIdx.y >> 3);   // gridDim.x==8
    int bx = blockIdx.y & 7;
    if (by >= R) return;
    int row0 = by * 128, col0 = bx * 128;

    int srow = tid >> 2;
    int skoff = (tid & 3) * 8;

    int wm = (w >> 1) * 64, wn = (w & 1) * 64;
    int fr = lane & 15;
    int fq = lane >> 4;

    f32x4 acc[4][4];
#pragma unroll
    for (int i = 0; i < 4; ++i)
#pragma unroll
        for (int j = 0; j < 4; ++j){ acc[i][j].x = 0.f; acc[i][j].y = 0.f; acc[i][j].z = 0.f; acc[i][j].w = 0.f; }

    int ra0 = row0 + srow;      if (ra0 >= M) ra0 = M - 1;
    int ra1 = row0 + srow + 64; if (ra1 >= M) ra1 = M - 1;
    int rb0 = col0 + srow;
    int rb1 = col0 + srow + 64;

    for (int k0 = 0; k0 < K; k0 += 32){
        size_t ga0 = (size_t)ra0 * K + k0 + skoff;
        size_t ga1 = (size_t)ra1 * K + k0 + skoff;
        size_t gb0 = (size_t)rb0 * K + k0 + skoff;
        size_t gb1 = (size_t)rb1 * K + k0 + skoff;
        gload_lds16(Ahi  + ga0, &As[0][srow     ][skoff]);
        gload_lds16(Ahi  + ga1, &As[0][srow + 64][skoff]);
        gload_lds16(Alo  + ga0, &As[1][srow     ][skoff]);
        gload_lds16(Alo  + ga1, &As[1][srow + 64][skoff]);
        gload_lds16(BThi + gb0, &Bs[0][srow     ][skoff]);
        gload_lds16(BThi + gb1, &Bs[0][srow + 64][skoff]);
        gload_lds16(BTlo + gb0, &Bs[1][srow     ][skoff]);
        gload_lds16(BTlo + gb1, &Bs[1][srow + 64][skoff]);
        __syncthreads();

        bf16x8 ah[4], al[4], bh[4], bl[4];
#pragma unroll
        for (int i = 0; i < 4; ++i){
            ah[i] = *(const bf16x8*)&As[0][wm + i * 16 + fr][fq * 8];
            al[i] = *(const bf16x8*)&As[1][wm + i * 16 + fr][fq * 8];
            bh[i] = *(const bf16x8*)&Bs[0][wn + i * 16 + fr][fq * 8];
            bl[i] = *(const bf16x8*)&Bs[1][wn + i * 16 + fr][fq * 8];
        }
#pragma unroll
        for (int i = 0; i < 4; ++i)
#pragma unroll
            for (int j = 0; j < 4; ++j){
                acc[i][j] = __builtin_amdgcn_mfma_f32_16x16x32_bf16(ah[i], bh[j], acc[i][j], 0, 0, 0);
                acc[i][j] = __builtin_amdgcn_mfma_f32_16x16x32_bf16(ah[i], bl[j], acc[i][j], 0, 0, 0);
                acc[i][j] = __builtin_amdgcn_mfma_f32_16x16x32_bf16(al[i], bh[j], acc[i][j], 0, 0, 0);
            }
        __syncthreads();
    }

    // bf16 C store (C/D layout: col=lane&15, row=(lane>>4)*4+reg)
#pragma unroll
    for (int i = 0; i < 4; ++i){
#pragma unroll
        for (int j = 0; j < 4; ++j){
            int colc = col0 + wn + j * 16 + fr;
#pragma unroll
            for (int r = 0; r < 4; ++r){
                int row = row0 + wm + i * 16 + fq * 4 + r;
                if (row < M) Cbf[(size_t)row * Nn + colc] = f2bf(acc[i][j][r]);
            }
        }
    }
}

// ---------------- per-node attention score dots (bf16 h) ----------------
__global__ __launch_bounds__(256) void k_esd(const u16* __restrict__ h, const float* __restrict__ asrc,
                                             const float* __restrict__ adst,
                                             float* __restrict__ es, float* __restrict__ ed){
    int n = blockIdx.x;
    int tid = threadIdx.x;
    int w = tid >> 6, lane = tid & 63;
    float4 hv = bf4_to_f4(*(const ushort4*)(h + (size_t)n * DHID + w * CPH + lane * 4));
    float4 av = *(const float4*)(asrc + w * CPH + lane * 4);
    float4 dv = *(const float4*)(adst + w * CPH + lane * 4);
    float s = hv.x * av.x + hv.y * av.y + hv.z * av.z + hv.w * av.w;
    float d = hv.x * dv.x + hv.y * dv.y + hv.z * dv.z + hv.w * dv.w;
    for (int off = 32; off > 0; off >>= 1){
        s += __shfl_down(s, off);
        d += __shfl_down(d, off);
    }
    if (lane == 0){ es[n * HEADS + w] = s; ed[n * HEADS + w] = d; }
}

// ---------------- segment softmax + aggregation (bf16 gather) + bias + elu + split write ----------------
__global__ __launch_bounds__(256) void k_agg(const u16* __restrict__ hsrc, const float* __restrict__ es,
                                             const float* __restrict__ ed, const int* __restrict__ rowptr,
                                             const int* __restrict__ col, const float* __restrict__ bias,
                                             u16* __restrict__ outhi, u16* __restrict__ outlo, int writeLo){
    int n = blockIdx.x;
    int tid = threadIdx.x;
    int w = tid >> 6, lane = tid & 63;
    int rp0 = rowptr[n];
    int deg = rowptr[n + 1] - rp0;
    int total = deg + 1;
    float4 edv = *(const float4*)(ed + (size_t)n * HEADS);

    __shared__ float4 sred[4];
    __shared__ float4 sbc;

    float4 mx = make_float4(-FLT_BIG, -FLT_BIG, -FLT_BIG, -FLT_BIG);
    for (int i = tid; i < total; i += 256){
        int s = (i < deg) ? col[rp0 + i] : n;
        float4 ev = *(const float4*)(es + (size_t)s * HEADS);
        mx.x = fmaxf(mx.x, lrelu(ev.x + edv.x));
        mx.y = fmaxf(mx.y, lrelu(ev.y + edv.y));
        mx.z = fmaxf(mx.z, lrelu(ev.z + edv.z));
        mx.w = fmaxf(mx.w, lrelu(ev.w + edv.w));
    }
    for (int off = 32; off > 0; off >>= 1){
        mx.x = fmaxf(mx.x, __shfl_down(mx.x, off));
        mx.y = fmaxf(mx.y, __shfl_down(mx.y, off));
        mx.z = fmaxf(mx.z, __shfl_down(mx.z, off));
        mx.w = fmaxf(mx.w, __shfl_down(mx.w, off));
    }
    if (lane == 0) sred[w] = mx;
    __syncthreads();
    if (tid == 0){
        float4 a = sred[0], b = sred[1], c = sred[2], d = sred[3];
        a.x = fmaxf(fmaxf(a.x, b.x), fmaxf(c.x, d.x));
        a.y = fmaxf(fmaxf(a.y, b.y), fmaxf(c.y, d.y));
        a.z = fmaxf(fmaxf(a.z, b.z), fmaxf(c.z, d.z));
        a.w = fmaxf(fmaxf(a.w, b.w), fmaxf(c.w, d.w));
        sbc = a;
    }
    __syncthreads();
    float4 m4 = sbc;

    float4 sm = make_float4(0.f, 0.f, 0.f, 0.f);
    for (int i = tid; i < total; i += 256){
        int s = (i < deg) ? col[rp0 + i] : n;
        float4 ev = *(const float4*)(es + (size_t)s * HEADS);
        sm.x += expf(lrelu(ev.x + edv.x) - m4.x);
        sm.y += expf(lrelu(ev.y + edv.y) - m4.y);
        sm.z += expf(lrelu(ev.z + edv.z) - m4.z);
        sm.w += expf(lrelu(ev.w + edv.w) - m4.w);
    }
    for (int off = 32; off > 0; off >>= 1){
        sm.x += __shfl_down(sm.x, off);
        sm.y += __shfl_down(sm.y, off);
        sm.z += __shfl_down(sm.z, off);
        sm.w += __shfl_down(sm.w, off);
    }
    if (lane == 0) sred[w] = sm;
    __syncthreads();
    if (tid == 0){
        float4 a = sred[0], b = sred[1], c = sred[2], d = sred[3];
        a.x += b.x + c.x + d.x;
        a.y += b.y + c.y + d.y;
        a.z += b.z + c.z + d.z;
        a.w += b.w + c.w + d.w;
        sbc = a;
    }
    __syncthreads();
    float4 s4 = sbc;

    float myM  = (w == 0) ? m4.x  : (w == 1) ? m4.y  : (w == 2) ? m4.z  : m4.w;
    float myS  = (w == 0) ? s4.x  : (w == 1) ? s4.y  : (w == 2) ? s4.z  : s4.w;
    float myEd = (w == 0) ? edv.x : (w == 1) ? edv.y : (w == 2) ? edv.z : edv.w;
    float myInv = 1.f / (myS + 1e-16f);
    int cidx = w * CPH + lane * 4;
    float4 acc = make_float4(0.f, 0.f, 0.f, 0.f);
    for (int i = 0; i < total; ++i){
        int s = (i < deg) ? col[rp0 + i] : n;
        float ei = es[(size_t)s * HEADS + w];
        float alpha = expf(lrelu(ei + myEd) - myM) * myInv;
        float4 hv = bf4_to_f4(*(const ushort4*)(hsrc + (size_t)s * DHID + cidx));
        acc.x += alpha * hv.x;
        acc.y += alpha * hv.y;
        acc.z += alpha * hv.z;
        acc.w += alpha * hv.w;
    }
    float4 bv = *(const float4*)(bias + cidx);
    float ox = eluf(acc.x + bv.x);
    float oy = eluf(acc.y + bv.y);
    float oz = eluf(acc.z + bv.z);
    float ow = eluf(acc.w + bv.w);
    ushort4 h4;
    h4.x = f2bf(ox); h4.y = f2bf(oy); h4.z = f2bf(oz); h4.w = f2bf(ow);
    *(ushort4*)(outhi + (size_t)n * DHID + cidx) = h4;
    if (writeLo){
        ushort4 l4;
        l4.x = f2bf(ox - bf2f(h4.x));
        l4.y = f2bf(oy - bf2f(h4.y));
        l4.z = f2bf(oz - bf2f(h4.z));
        l4.w = f2bf(ow - bf2f(h4.w));
        *(ushort4*)(outlo + (size_t)n * DHID + cidx) = l4;
    }
}

// ---------------- two-stage per-graph mean/max pooling (bf16 input) ----------------
__global__ __launch_bounds__(256) void k_pool_init(float* __restrict__ gsum, float* __restrict__ gmax, int L){
    int i = blockIdx.x * blockDim.x + threadIdx.x;
    if (i < L){ gsum[i] = 0.f; gmax[i] = -FLT_BIG; }
}

__global__ __launch_bounds__(256) void k_pool_partial(const u16* __restrict__ hf,
                                                      const int* __restrict__ batch,
                                                      float* __restrict__ gsum, float* __restrict__ gmax,
                                                      int N){
    int c = blockIdx.y * 256 + threadIdx.x;
    int i0 = blockIdx.x * PCHUNK;
    int i1 = i0 + PCHUNK; if (i1 > N) i1 = N;
    int curg = batch[i0];
    float s = 0.f, m = -FLT_BIG;
    for (int i = i0; i < i1; ++i){
        int g = batch[i];
        if (g != curg){
            atomicAdd(&gsum[(size_t)curg * DHID + c], s);
            atomicMaxF(&gmax[(size_t)curg * DHID + c], m);
            s = 0.f; m = -FLT_BIG; curg = g;
        }
        float v = bf2f(hf[(size_t)i * DHID + c]);
        s += v;
        m = fmaxf(m, v);
    }
    atomicAdd(&gsum[(size_t)curg * DHID + c], s);
    atomicMaxF(&gmax[(size_t)curg * DHID + c], m);
}

__global__ __launch_bounds__(256) void k_pool_final(const float* __restrict__ gsum,
                                                    const float* __restrict__ gmax,
                                                    const int* __restrict__ lo, const int* __restrict__ hi,
                                                    float* __restrict__ gfeat){
    int g = blockIdx.x;
    int c = threadIdx.x * 4;
    int l = lo[g], h2 = hi[g];
    int cnt = (h2 > l) ? (h2 - l) : 0;
    float invc = 1.f / (float)((cnt > 1) ? cnt : 1);
    float4 s = *(const float4*)(gsum + (size_t)g * DHID + c);
    float4 m = *(const float4*)(gmax + (size_t)g * DHID + c);
    float4 mean = make_float4(s.x * invc, s.y * invc, s.z * invc, s.w * invc);
    if (cnt == 0) m = make_float4(0.f, 0.f, 0.f, 0.f);
    *(float4*)(gfeat + (size_t)g * 2048 + c)        = mean;
    *(float4*)(gfeat + (size_t)g * 2048 + 1024 + c) = m;
}

// ---------------- small FC ----------------
__global__ __launch_bounds__(256) void k_fc(const float* __restrict__ X, const float* __restrict__ W,
                                            const float* __restrict__ b, float* __restrict__ Y,
                                            int K, int Nc, int relu){
    __shared__ float xr[2048];
    int r = blockIdx.y;
    int tid = threadIdx.x;
    for (int i = tid; i < K; i += 256) xr[i] = X[(size_t)r * K + i];
    __syncthreads();
    int c = blockIdx.x * 256 + tid;
    if (c >= Nc) return;
    float acc = b[c];
    for (int k = 0; k < K; ++k) acc += xr[k] * W[(size_t)k * Nc + c];
    if (relu) acc = fmaxf(acc, 0.f);
    Y[(size_t)r * Nc + c] = acc;
}

// ---------------- launch ----------------
extern "C" void kernel_launch(void* const* d_in, const int* in_sizes, int n_in,
                              void* d_out, int out_size, void* d_ws, size_t ws_size,
                              hipStream_t stream) {
    const float* x      = (const float*)d_in[0];
    const int*   ei     = (const int*)  d_in[1];
    const int*   batch  = (const int*)  d_in[2];
    const float* W1     = (const float*)d_in[3];
    const float* asrc1  = (const float*)d_in[4];
    const float* adst1  = (const float*)d_in[5];
    const float* b1     = (const float*)d_in[6];
    const float* W2     = (const float*)d_in[7];
    const float* asrc2  = (const float*)d_in[8];
    const float* adst2  = (const float*)d_in[9];
    const float* b2     = (const float*)d_in[10];
    const float* Wc1    = (const float*)d_in[11];
    const float* bc1    = (const float*)d_in[12];
    const float* Wc2    = (const float*)d_in[13];
    const float* bc2    = (const float*)d_in[14];
    const float* Wc3    = (const float*)d_in[15];
    const float* bc3    = (const float*)d_in[16];

    const int N = in_sizes[2];
    const int E = in_sizes[1] / 2;
    const int G = out_size / 5;
    const int DIN = in_sizes[0] / N;

    const int* srcI = ei;
    const int* dstI = ei + E;

    char* p = (char*)d_ws;
    auto alloc = [&](size_t bytes) -> void* {
        void* q = (void*)p;
        p += (bytes + 255) & ~(size_t)255;
        return q;
    };
    u16*   R1     = (u16*)alloc((size_t)N * DHID * 2 * 2);   // activations hi+lo
    u16*   R2     = (u16*)alloc((size_t)N * DHID * 2);       // bf16 h plane
    float* es     = (float*)alloc((size_t)N * HEADS * 4);
    float* ed     = (float*)alloc((size_t)N * HEADS * 4);
    float* gfeat  = (float*)alloc((size_t)G * 2048 * 4);
    float* gsum   = (float*)alloc((size_t)G * DHID * 4);
    float* gmax   = (float*)alloc((size_t)G * DHID * 4);
    float* z1     = (float*)alloc((size_t)G * 512 * 4);
    float* z2     = (float*)alloc((size_t)G * 256 * 4);
    int*   cnt    = (int*)  alloc((size_t)N * 4);
    int*   fill   = (int*)  alloc((size_t)N * 4);
    int*   rowptr = (int*)  alloc((size_t)(N + 1) * 4);
    int*   col    = (int*)  alloc((size_t)E * 4);
    int*   lo     = (int*)  alloc((size_t)G * 4);
    int*   hi     = (int*)  alloc((size_t)G * 4);
    u16*   w1th   = (u16*)  alloc((size_t)DIN * DHID * 2);
    u16*   w1tl   = (u16*)  alloc((size_t)DIN * DHID * 2);
    u16*   w2th   = (u16*)  alloc((size_t)DHID * DHID * 2);
    u16*   w2tl   = (u16*)  alloc((size_t)DHID * DHID * 2);
    float* logits = (float*)d_out;

    int nb = (N + 255) / 256;
    int ebp = (E + 255) / 256;

    // CSR + pooling bounds
    k_init   <<<nb,  256, 0, stream>>>(cnt, fill, lo, hi, N, G);
    k_count  <<<ebp, 256, 0, stream>>>(dstI, cnt, E);
    k_scan   <<<1,  1024, 0, stream>>>(cnt, rowptr, N, E);
    k_scatter<<<ebp, 256, 0, stream>>>(srcI, dstI, rowptr, fill, col, E);
    k_bounds <<<nb,  256, 0, stream>>>(batch, lo, hi, N);

    // weight splits (with transpose)
    k_splitT<<<(DIN * DHID + 255) / 256, 256, 0, stream>>>(W1, w1th, w1tl, DIN, DHID);
    k_splitT<<<(DHID * DHID + 255) / 256, 256, 0, stream>>>(W2, w2th, w2tl, DHID, DHID);

    int R = (N + 127) / 128;
    int Rchunk = (R + 7) / 8;
    dim3 gemmGrd(8, 8 * Rchunk);   // swizzled: x = XCD row-chunk, y = (local row, col-block)

    // ---- GAT layer 1 ----
    u16* a1h = R1;
    u16* a1l = R1 + (size_t)N * DIN;
    long L41 = (long)N * DIN / 4;
    k_split<<<(unsigned)((L41 + 255) / 256), 256, 0, stream>>>(x, a1h, a1l, L41);
    u16* h1 = R2;
    k_gemm_mfma<<<gemmGrd, 256, 0, stream>>>(a1h, a1l, w1th, w1tl, h1, N, DIN, DHID, Rchunk);
    k_esd<<<N, 256, 0, stream>>>(h1, asrc1, adst1, es, ed);
    u16* o1h = R1;
    u16* o1l = R1 + (size_t)N * DHID;
    k_agg<<<N, 256, 0, stream>>>(h1, es, ed, rowptr, col, b1, o1h, o1l, 1);

    // ---- GAT layer 2 ----
    u16* h2 = R2;
    k_gemm_mfma<<<gemmGrd, 256, 0, stream>>>(o1h, o1l, w2th, w2tl, h2, N, DHID, DHID, Rchunk);
    k_esd<<<N, 256, 0, stream>>>(h2, asrc2, adst2, es, ed);
    u16* o2h = R1;
    k_agg<<<N, 256, 0, stream>>>(h2, es, ed, rowptr, col, b2, o2h, (u16*)0, 0);

    // ---- pooling + classifier ----
    k_pool_init<<<(G * DHID + 255) / 256, 256, 0, stream>>>(gsum, gmax, G * DHID);
    dim3 poolGrd((N + PCHUNK - 1) / PCHUNK, DHID / 256);
    k_pool_partial<<<poolGrd, 256, 0, stream>>>(o2h, batch, gsum, gmax, N);
    k_pool_final<<<G, 256, 0, stream>>>(gsum, gmax, lo, hi, gfeat);

    k_fc<<<dim3(2, G), 256, 0, stream>>>(gfeat, Wc1, bc1, z1, 2048, 512, 1);
    k_fc<<<dim3(1, G), 256, 0, stream>>>(z1,    Wc2, bc2, z2, 512,  256, 1);
    k_fc<<<dim3(1, G), 256, 0, stream>>>(z2,    Wc3, bc3, logits, 256, 5, 0);
}

// Round 6
// 1837.808 us; speedup vs baseline: 2.2704x; 1.0875x over previous
//
#include <hip/hip_runtime.h>
#include <math.h>

#define HEADS 4
#define CPH 256
#define DHID 1024
#define NEG_SLOPE 0.2f
#define FLT_BIG 3.402823466e38f
#define PCHUNK 128

typedef unsigned short u16;
typedef __bf16 bf16x8 __attribute__((ext_vector_type(8)));
typedef float f32x4 __attribute__((ext_vector_type(4)));

__device__ __forceinline__ float lrelu(float x){ return x > 0.f ? x : NEG_SLOPE * x; }
__device__ __forceinline__ float eluf(float x){ return x > 0.f ? x : expf(x) - 1.f; }

__device__ __forceinline__ u16 f2bf(float f){
    unsigned u = __float_as_uint(f);
    u += 0x7fffu + ((u >> 16) & 1u);
    return (u16)(u >> 16);
}
__device__ __forceinline__ float bf2f(u16 h){ return __uint_as_float(((unsigned)h) << 16); }
__device__ __forceinline__ float4 bf4_to_f4(ushort4 u){
    return make_float4(bf2f(u.x), bf2f(u.y), bf2f(u.z), bf2f(u.w));
}

__device__ __forceinline__ void gload_lds16(const void* g, void* l){
    __builtin_amdgcn_global_load_lds((const __attribute__((address_space(1))) unsigned int*)g,
                                     (__attribute__((address_space(3))) unsigned int*)l, 16, 0, 0);
}

__device__ __forceinline__ void atomicMaxF(float* addr, float v){
    if (v >= 0.f) atomicMax((int*)addr, __float_as_int(v));
    else          atomicMin((unsigned int*)addr, __float_as_uint(v));
}

// ---------------- CSR build + pooling bounds ----------------
__global__ void k_init(int* cnt, int* fill, int* lo, int* hi, int N, int G){
    int i = blockIdx.x * blockDim.x + threadIdx.x;
    if (i < N){ cnt[i] = 0; fill[i] = 0; }
    if (i < G){ lo[i] = 0x7fffffff; hi[i] = 0; }
}

__global__ void k_count(const int* __restrict__ dst, int* __restrict__ cnt, int E){
    int e = blockIdx.x * blockDim.x + threadIdx.x;
    if (e < E) atomicAdd(&cnt[dst[e]], 1);
}

__global__ __launch_bounds__(1024) void k_scan(const int* __restrict__ cnt, int* __restrict__ rowptr,
                                               int N, int E){
    __shared__ int tot[1024];
    int tid = threadIdx.x;
    int items = (N + 1023) >> 10;
    int base = tid * items;
    int sum = 0;
    for (int i = 0; i < items; ++i){ int idx = base + i; if (idx < N) sum += cnt[idx]; }
    tot[tid] = sum;
    __syncthreads();
    for (int off = 1; off < 1024; off <<= 1){
        int t = (tid >= off) ? tot[tid - off] : 0;
        __syncthreads();
        tot[tid] += t;
        __syncthreads();
    }
    int run = tot[tid] - sum;
    for (int i = 0; i < items; ++i){
        int idx = base + i;
        if (idx < N){ rowptr[idx] = run; run += cnt[idx]; }
    }
    if (tid == 0) rowptr[N] = E;
}

__global__ void k_scatter(const int* __restrict__ src, const int* __restrict__ dst,
                          const int* __restrict__ rowptr, int* __restrict__ fill,
                          int* __restrict__ col, int E){
    int e = blockIdx.x * blockDim.x + threadIdx.x;
    if (e < E){
        int d = dst[e];
        int pos = rowptr[d] + atomicAdd(&fill[d], 1);
        col[pos] = src[e];
    }
}

__global__ void k_bounds(const int* __restrict__ batch, int* lo, int* hi, int N){
    int i = blockIdx.x * blockDim.x + threadIdx.x;
    if (i < N){
        int b = batch[i];
        atomicMin(&lo[b], i);
        atomicMax(&hi[b], i + 1);
    }
}

// ---------------- split kernels ----------------
__global__ void k_split(const float* __restrict__ X, u16* __restrict__ hi, u16* __restrict__ lo, long L4){
    long i = (long)blockIdx.x * blockDim.x + threadIdx.x;
    if (i < L4){
        float4 v = ((const float4*)X)[i];
        ushort4 h, l;
        h.x = f2bf(v.x); l.x = f2bf(v.x - bf2f(h.x));
        h.y = f2bf(v.y); l.y = f2bf(v.y - bf2f(h.y));
        h.z = f2bf(v.z); l.z = f2bf(v.z - bf2f(h.z));
        h.w = f2bf(v.w); l.w = f2bf(v.w - bf2f(h.w));
        ((ushort4*)hi)[i] = h;
        ((ushort4*)lo)[i] = l;
    }
}

__global__ void k_splitT(const float* __restrict__ W, u16* __restrict__ hiT, u16* __restrict__ loT,
                         int K, int Nn){
    int idx = blockIdx.x * blockDim.x + threadIdx.x;
    if (idx < K * Nn){
        int k = idx / Nn, n = idx - k * Nn;
        float v = W[idx];
        u16 h = f2bf(v);
        hiT[(size_t)n * K + k] = h;
        loT[(size_t)n * K + k] = f2bf(v - bf2f(h));
    }
}

// ---------------- split-bf16 MFMA GEMM, bf16 C store ----------------
__global__ __launch_bounds__(256) void k_gemm_mfma(
    const u16* __restrict__ Ahi, const u16* __restrict__ Alo,
    const u16* __restrict__ BThi, const u16* __restrict__ BTlo,
    u16* __restrict__ Cbf, int M, int K, int Nn, int Rchunk)
{
    __shared__ __align__(16) u16 As[2][128][32];
    __shared__ __align__(16) u16 Bs[2][128][32];
    int tid = threadIdx.x;
    int w = tid >> 6, lane = tid & 63;

    int R = (M + 127) >> 7;
    int by = blockIdx.x * Rchunk + (blockIdx.y >> 3);   // gridDim.x==8 (XCD swizzle)
    int bx = blockIdx.y & 7;
    if (by >= R) return;
    int row0 = by * 128, col0 = bx * 128;

    int srow = tid >> 2;
    int skoff = (tid & 3) * 8;

    int wm = (w >> 1) * 64, wn = (w & 1) * 64;
    int fr = lane & 15;
    int fq = lane >> 4;

    f32x4 acc[4][4];
#pragma unroll
    for (int i = 0; i < 4; ++i)
#pragma unroll
        for (int j = 0; j < 4; ++j){ acc[i][j].x = 0.f; acc[i][j].y = 0.f; acc[i][j].z = 0.f; acc[i][j].w = 0.f; }

    int ra0 = row0 + srow;      if (ra0 >= M) ra0 = M - 1;
    int ra1 = row0 + srow + 64; if (ra1 >= M) ra1 = M - 1;
    int rb0 = col0 + srow;
    int rb1 = col0 + srow + 64;

    for (int k0 = 0; k0 < K; k0 += 32){
        size_t ga0 = (size_t)ra0 * K + k0 + skoff;
        size_t ga1 = (size_t)ra1 * K + k0 + skoff;
        size_t gb0 = (size_t)rb0 * K + k0 + skoff;
        size_t gb1 = (size_t)rb1 * K + k0 + skoff;
        gload_lds16(Ahi  + ga0, &As[0][srow     ][skoff]);
        gload_lds16(Ahi  + ga1, &As[0][srow + 64][skoff]);
        gload_lds16(Alo  + ga0, &As[1][srow     ][skoff]);
        gload_lds16(Alo  + ga1, &As[1][srow + 64][skoff]);
        gload_lds16(BThi + gb0, &Bs[0][srow     ][skoff]);
        gload_lds16(BThi + gb1, &Bs[0][srow + 64][skoff]);
        gload_lds16(BTlo + gb0, &Bs[1][srow     ][skoff]);
        gload_lds16(BTlo + gb1, &Bs[1][srow + 64][skoff]);
        __syncthreads();

        bf16x8 ah[4], al[4], bh[4], bl[4];
#pragma unroll
        for (int i = 0; i < 4; ++i){
            ah[i] = *(const bf16x8*)&As[0][wm + i * 16 + fr][fq * 8];
            al[i] = *(const bf16x8*)&As[1][wm + i * 16 + fr][fq * 8];
            bh[i] = *(const bf16x8*)&Bs[0][wn + i * 16 + fr][fq * 8];
            bl[i] = *(const bf16x8*)&Bs[1][wn + i * 16 + fr][fq * 8];
        }
#pragma unroll
        for (int i = 0; i < 4; ++i)
#pragma unroll
            for (int j = 0; j < 4; ++j){
                acc[i][j] = __builtin_amdgcn_mfma_f32_16x16x32_bf16(ah[i], bh[j], acc[i][j], 0, 0, 0);
                acc[i][j] = __builtin_amdgcn_mfma_f32_16x16x32_bf16(ah[i], bl[j], acc[i][j], 0, 0, 0);
                acc[i][j] = __builtin_amdgcn_mfma_f32_16x16x32_bf16(al[i], bh[j], acc[i][j], 0, 0, 0);
            }
        __syncthreads();
    }

#pragma unroll
    for (int i = 0; i < 4; ++i){
#pragma unroll
        for (int j = 0; j < 4; ++j){
            int colc = col0 + wn + j * 16 + fr;
#pragma unroll
            for (int r = 0; r < 4; ++r){
                int row = row0 + wm + i * 16 + fq * 4 + r;
                if (row < M) Cbf[(size_t)row * Nn + colc] = f2bf(acc[i][j][r]);
            }
        }
    }
}

// ---------------- per-node attention score dots (bf16 h) ----------------
__global__ __launch_bounds__(256) void k_esd(const u16* __restrict__ h, const float* __restrict__ asrc,
                                             const float* __restrict__ adst,
                                             float* __restrict__ es, float* __restrict__ ed){
    int n = blockIdx.x;
    int tid = threadIdx.x;
    int w = tid >> 6, lane = tid & 63;
    float4 hv = bf4_to_f4(*(const ushort4*)(h + (size_t)n * DHID + w * CPH + lane * 4));
    float4 av = *(const float4*)(asrc + w * CPH + lane * 4);
    float4 dv = *(const float4*)(adst + w * CPH + lane * 4);
    float s = hv.x * av.x + hv.y * av.y + hv.z * av.z + hv.w * av.w;
    float d = hv.x * dv.x + hv.y * dv.y + hv.z * dv.z + hv.w * dv.w;
    for (int off = 32; off > 0; off >>= 1){
        s += __shfl_down(s, off);
        d += __shfl_down(d, off);
    }
    if (lane == 0){ es[n * HEADS + w] = s; ed[n * HEADS + w] = d; }
}

// ---------------- wave-per-node segment softmax + aggregation + bias + elu + split write ----------------
// block = 256 threads = 4 waves, wave i handles node blockIdx.x*4+i.
// Lane covers channels {h*256 + lane*4 ..+3} for all 4 heads -> full 2KB contiguous row per edge.
__global__ __launch_bounds__(256) void k_agg(const u16* __restrict__ hsrc, const float* __restrict__ es,
                                             const float* __restrict__ ed, const int* __restrict__ rowptr,
                                             const int* __restrict__ col, const float* __restrict__ bias,
                                             u16* __restrict__ outhi, u16* __restrict__ outlo,
                                             int writeLo, int N){
    int n = blockIdx.x * 4 + (threadIdx.x >> 6);
    if (n >= N) return;
    int lane = threadIdx.x & 63;
    int rp0 = rowptr[n];
    int deg = rowptr[n + 1] - rp0;
    int total = deg + 1;                         // + implicit self-loop
    float4 edv = *(const float4*)(ed + (size_t)n * HEADS);

    // pass 1: per-head max over incoming edges
    float4 mx = make_float4(-FLT_BIG, -FLT_BIG, -FLT_BIG, -FLT_BIG);
    for (int i = lane; i < total; i += 64){
        int s = (i < deg) ? col[rp0 + i] : n;
        float4 ev = *(const float4*)(es + (size_t)s * HEADS);
        mx.x = fmaxf(mx.x, lrelu(ev.x + edv.x));
        mx.y = fmaxf(mx.y, lrelu(ev.y + edv.y));
        mx.z = fmaxf(mx.z, lrelu(ev.z + edv.z));
        mx.w = fmaxf(mx.w, lrelu(ev.w + edv.w));
    }
#pragma unroll
    for (int off = 1; off < 64; off <<= 1){
        mx.x = fmaxf(mx.x, __shfl_xor(mx.x, off));
        mx.y = fmaxf(mx.y, __shfl_xor(mx.y, off));
        mx.z = fmaxf(mx.z, __shfl_xor(mx.z, off));
        mx.w = fmaxf(mx.w, __shfl_xor(mx.w, off));
    }

    // pass 2: per-head sum of exp(e - m)  (es now L1-hot)
    float4 sm = make_float4(0.f, 0.f, 0.f, 0.f);
    for (int i = lane; i < total; i += 64){
        int s = (i < deg) ? col[rp0 + i] : n;
        float4 ev = *(const float4*)(es + (size_t)s * HEADS);
        sm.x += expf(lrelu(ev.x + edv.x) - mx.x);
        sm.y += expf(lrelu(ev.y + edv.y) - mx.y);
        sm.z += expf(lrelu(ev.z + edv.z) - mx.z);
        sm.w += expf(lrelu(ev.w + edv.w) - mx.w);
    }
#pragma unroll
    for (int off = 1; off < 64; off <<= 1){
        sm.x += __shfl_xor(sm.x, off);
        sm.y += __shfl_xor(sm.y, off);
        sm.z += __shfl_xor(sm.z, off);
        sm.w += __shfl_xor(sm.w, off);
    }
    float4 inv = make_float4(1.f / (sm.x + 1e-16f), 1.f / (sm.y + 1e-16f),
                             1.f / (sm.z + 1e-16f), 1.f / (sm.w + 1e-16f));

    // pass 3: weighted aggregation — wave reads the full 2KB row per edge (4 x 512B)
    float4 a0 = make_float4(0.f,0.f,0.f,0.f), a1 = a0, a2 = a0, a3 = a0;
    int c4 = lane * 4;
    for (int i = 0; i < total; ++i){
        int s = (i < deg) ? col[rp0 + i] : n;           // wave-uniform
        float4 ev = *(const float4*)(es + (size_t)s * HEADS);   // L1-hot broadcast
        const u16* rowp = hsrc + (size_t)s * DHID;
        ushort4 r0 = *(const ushort4*)(rowp + 0 * CPH + c4);
        ushort4 r1 = *(const ushort4*)(rowp + 1 * CPH + c4);
        ushort4 r2 = *(const ushort4*)(rowp + 2 * CPH + c4);
        ushort4 r3 = *(const ushort4*)(rowp + 3 * CPH + c4);
        float alx = expf(lrelu(ev.x + edv.x) - mx.x) * inv.x;
        float aly = expf(lrelu(ev.y + edv.y) - mx.y) * inv.y;
        float alz = expf(lrelu(ev.z + edv.z) - mx.z) * inv.z;
        float alw = expf(lrelu(ev.w + edv.w) - mx.w) * inv.w;
        float4 f0 = bf4_to_f4(r0), f1 = bf4_to_f4(r1), f2 = bf4_to_f4(r2), f3 = bf4_to_f4(r3);
        a0.x = fmaf(alx, f0.x, a0.x); a0.y = fmaf(alx, f0.y, a0.y);
        a0.z = fmaf(alx, f0.z, a0.z); a0.w = fmaf(alx, f0.w, a0.w);
        a1.x = fmaf(aly, f1.x, a1.x); a1.y = fmaf(aly, f1.y, a1.y);
        a1.z = fmaf(aly, f1.z, a1.z); a1.w = fmaf(aly, f1.w, a1.w);
        a2.x = fmaf(alz, f2.x, a2.x); a2.y = fmaf(alz, f2.y, a2.y);
        a2.z = fmaf(alz, f2.z, a2.z); a2.w = fmaf(alz, f2.w, a2.w);
        a3.x = fmaf(alw, f3.x, a3.x); a3.y = fmaf(alw, f3.y, a3.y);
        a3.z = fmaf(alw, f3.z, a3.z); a3.w = fmaf(alw, f3.w, a3.w);
    }

    // epilogue: +bias, elu, bf16 hi(/lo) store per head
#pragma unroll
    for (int h = 0; h < 4; ++h){
        float4 a = (h == 0) ? a0 : (h == 1) ? a1 : (h == 2) ? a2 : a3;
        int cidx = h * CPH + c4;
        float4 bv = *(const float4*)(bias + cidx);
        float ox = eluf(a.x + bv.x);
        float oy = eluf(a.y + bv.y);
        float oz = eluf(a.z + bv.z);
        float ow = eluf(a.w + bv.w);
        ushort4 h4;
        h4.x = f2bf(ox); h4.y = f2bf(oy); h4.z = f2bf(oz); h4.w = f2bf(ow);
        *(ushort4*)(outhi + (size_t)n * DHID + cidx) = h4;
        if (writeLo){
            ushort4 l4;
            l4.x = f2bf(ox - bf2f(h4.x));
            l4.y = f2bf(oy - bf2f(h4.y));
            l4.z = f2bf(oz - bf2f(h4.z));
            l4.w = f2bf(ow - bf2f(h4.w));
            *(ushort4*)(outlo + (size_t)n * DHID + cidx) = l4;
        }
    }
}

// ---------------- two-stage per-graph mean/max pooling (bf16 input) ----------------
__global__ __launch_bounds__(256) void k_pool_init(float* __restrict__ gsum, float* __restrict__ gmax, int L){
    int i = blockIdx.x * blockDim.x + threadIdx.x;
    if (i < L){ gsum[i] = 0.f; gmax[i] = -FLT_BIG; }
}

__global__ __launch_bounds__(256) void k_pool_partial(const u16* __restrict__ hf,
                                                      const int* __restrict__ batch,
                                                      float* __restrict__ gsum, float* __restrict__ gmax,
                                                      int N){
    int c = blockIdx.y * 256 + threadIdx.x;
    int i0 = blockIdx.x * PCHUNK;
    int i1 = i0 + PCHUNK; if (i1 > N) i1 = N;
    int curg = batch[i0];
    float s = 0.f, m = -FLT_BIG;
    for (int i = i0; i < i1; ++i){
        int g = batch[i];
        if (g != curg){
            atomicAdd(&gsum[(size_t)curg * DHID + c], s);
            atomicMaxF(&gmax[(size_t)curg * DHID + c], m);
            s = 0.f; m = -FLT_BIG; curg = g;
        }
        float v = bf2f(hf[(size_t)i * DHID + c]);
        s += v;
        m = fmaxf(m, v);
    }
    atomicAdd(&gsum[(size_t)curg * DHID + c], s);
    atomicMaxF(&gmax[(size_t)curg * DHID + c], m);
}

__global__ __launch_bounds__(256) void k_pool_final(const float* __restrict__ gsum,
                                                    const float* __restrict__ gmax,
                                                    const int* __restrict__ lo, const int* __restrict__ hi,
                                                    float* __restrict__ gfeat){
    int g = blockIdx.x;
    int c = threadIdx.x * 4;
    int l = lo[g], h2 = hi[g];
    int cnt = (h2 > l) ? (h2 - l) : 0;
    float invc = 1.f / (float)((cnt > 1) ? cnt : 1);
    float4 s = *(const float4*)(gsum + (size_t)g * DHID + c);
    float4 m = *(const float4*)(gmax + (size_t)g * DHID + c);
    float4 mean = make_float4(s.x * invc, s.y * invc, s.z * invc, s.w * invc);
    if (cnt == 0) m = make_float4(0.f, 0.f, 0.f, 0.f);
    *(float4*)(gfeat + (size_t)g * 2048 + c)        = mean;
    *(float4*)(gfeat + (size_t)g * 2048 + 1024 + c) = m;
}

// ---------------- small FC ----------------
__global__ __launch_bounds__(256) void k_fc(const float* __restrict__ X, const float* __restrict__ W,
                                            const float* __restrict__ b, float* __restrict__ Y,
                                            int K, int Nc, int relu){
    __shared__ float xr[2048];
    int r = blockIdx.y;
    int tid = threadIdx.x;
    for (int i = tid; i < K; i += 256) xr[i] = X[(size_t)r * K + i];
    __syncthreads();
    int c = blockIdx.x * 256 + tid;
    if (c >= Nc) return;
    float acc = b[c];
    for (int k = 0; k < K; ++k) acc += xr[k] * W[(size_t)k * Nc + c];
    if (relu) acc = fmaxf(acc, 0.f);
    Y[(size_t)r * Nc + c] = acc;
}

// ---------------- launch ----------------
extern "C" void kernel_launch(void* const* d_in, const int* in_sizes, int n_in,
                              void* d_out, int out_size, void* d_ws, size_t ws_size,
                              hipStream_t stream) {
    const float* x      = (const float*)d_in[0];
    const int*   ei     = (const int*)  d_in[1];
    const int*   batch  = (const int*)  d_in[2];
    const float* W1     = (const float*)d_in[3];
    const float* asrc1  = (const float*)d_in[4];
    const float* adst1  = (const float*)d_in[5];
    const float* b1     = (const float*)d_in[6];
    const float* W2     = (const float*)d_in[7];
    const float* asrc2  = (const float*)d_in[8];
    const float* adst2  = (const float*)d_in[9];
    const float* b2     = (const float*)d_in[10];
    const float* Wc1    = (const float*)d_in[11];
    const float* bc1    = (const float*)d_in[12];
    const float* Wc2    = (const float*)d_in[13];
    const float* bc2    = (const float*)d_in[14];
    const float* Wc3    = (const float*)d_in[15];
    const float* bc3    = (const float*)d_in[16];

    const int N = in_sizes[2];
    const int E = in_sizes[1] / 2;
    const int G = out_size / 5;
    const int DIN = in_sizes[0] / N;

    const int* srcI = ei;
    const int* dstI = ei + E;

    char* p = (char*)d_ws;
    auto alloc = [&](size_t bytes) -> void* {
        void* q = (void*)p;
        p += (bytes + 255) & ~(size_t)255;
        return q;
    };
    u16*   R1     = (u16*)alloc((size_t)N * DHID * 2 * 2);   // activations hi+lo
    u16*   R2     = (u16*)alloc((size_t)N * DHID * 2);       // bf16 h plane
    float* es     = (float*)alloc((size_t)N * HEADS * 4);
    float* ed     = (float*)alloc((size_t)N * HEADS * 4);
    float* gfeat  = (float*)alloc((size_t)G * 2048 * 4);
    float* gsum   = (float*)alloc((size_t)G * DHID * 4);
    float* gmax   = (float*)alloc((size_t)G * DHID * 4);
    float* z1     = (float*)alloc((size_t)G * 512 * 4);
    float* z2     = (float*)alloc((size_t)G * 256 * 4);
    int*   cnt    = (int*)  alloc((size_t)N * 4);
    int*   fill   = (int*)  alloc((size_t)N * 4);
    int*   rowptr = (int*)  alloc((size_t)(N + 1) * 4);
    int*   col    = (int*)  alloc((size_t)E * 4);
    int*   lo     = (int*)  alloc((size_t)G * 4);
    int*   hi     = (int*)  alloc((size_t)G * 4);
    u16*   w1th   = (u16*)  alloc((size_t)DIN * DHID * 2);
    u16*   w1tl   = (u16*)  alloc((size_t)DIN * DHID * 2);
    u16*   w2th   = (u16*)  alloc((size_t)DHID * DHID * 2);
    u16*   w2tl   = (u16*)  alloc((size_t)DHID * DHID * 2);
    float* logits = (float*)d_out;

    int nb = (N + 255) / 256;
    int ebp = (E + 255) / 256;
    int aggb = (N + 3) / 4;

    // CSR + pooling bounds
    k_init   <<<nb,  256, 0, stream>>>(cnt, fill, lo, hi, N, G);
    k_count  <<<ebp, 256, 0, stream>>>(dstI, cnt, E);
    k_scan   <<<1,  1024, 0, stream>>>(cnt, rowptr, N, E);
    k_scatter<<<ebp, 256, 0, stream>>>(srcI, dstI, rowptr, fill, col, E);
    k_bounds <<<nb,  256, 0, stream>>>(batch, lo, hi, N);

    // weight splits (with transpose)
    k_splitT<<<(DIN * DHID + 255) / 256, 256, 0, stream>>>(W1, w1th, w1tl, DIN, DHID);
    k_splitT<<<(DHID * DHID + 255) / 256, 256, 0, stream>>>(W2, w2th, w2tl, DHID, DHID);

    int R = (N + 127) / 128;
    int Rchunk = (R + 7) / 8;
    dim3 gemmGrd(8, 8 * Rchunk);   // XCD swizzle: x = row-chunk, y = (local row, col-block)

    // ---- GAT layer 1 ----
    u16* a1h = R1;
    u16* a1l = R1 + (size_t)N * DIN;
    long L41 = (long)N * DIN / 4;
    k_split<<<(unsigned)((L41 + 255) / 256), 256, 0, stream>>>(x, a1h, a1l, L41);
    u16* h1 = R2;
    k_gemm_mfma<<<gemmGrd, 256, 0, stream>>>(a1h, a1l, w1th, w1tl, h1, N, DIN, DHID, Rchunk);
    k_esd<<<N, 256, 0, stream>>>(h1, asrc1, adst1, es, ed);
    u16* o1h = R1;
    u16* o1l = R1 + (size_t)N * DHID;
    k_agg<<<aggb, 256, 0, stream>>>(h1, es, ed, rowptr, col, b1, o1h, o1l, 1, N);

    // ---- GAT layer 2 ----
    u16* h2 = R2;
    k_gemm_mfma<<<gemmGrd, 256, 0, stream>>>(o1h, o1l, w2th, w2tl, h2, N, DHID, DHID, Rchunk);
    k_esd<<<N, 256, 0, stream>>>(h2, asrc2, adst2, es, ed);
    u16* o2h = R1;
    k_agg<<<aggb, 256, 0, stream>>>(h2, es, ed, rowptr, col, b2, o2h, (u16*)0, 0, N);

    // ---- pooling + classifier ----
    k_pool_init<<<(G * DHID + 255) / 256, 256, 0, stream>>>(gsum, gmax, G * DHID);
    dim3 poolGrd((N + PCHUNK - 1) / PCHUNK, DHID / 256);
    k_pool_partial<<<poolGrd, 256, 0, stream>>>(o2h, batch, gsum, gmax, N);
    k_pool_final<<<G, 256, 0, stream>>>(gsum, gmax, lo, hi, gfeat);

    k_fc<<<dim3(2, G), 256, 0, stream>>>(gfeat, Wc1, bc1, z1, 2048, 512, 1);
    k_fc<<<dim3(1, G), 256, 0, stream>>>(z1,    Wc2, bc2, z2, 512,  256, 1);
    k_fc<<<dim3(1, G), 256, 0, stream>>>(z2,    Wc3, bc3, logits, 256, 5, 0);
}